// Round 10
// baseline (1840.505 us; speedup 1.0000x reference)
//
#include <hip/hip_runtime.h>
#include <hip/hip_bf16.h>

#define DEV __device__ __forceinline__
using bf16 = __hip_bfloat16;

static constexpr int B_ = 2, N_ = 4096, M_ = 512, K_ = 50;
static constexpr int BN = B_ * N_;   // 8192 points
static constexpr int BM = B_ * M_;   // 1024 grid points
static constexpr float EPS_ = 1e-5f;

DEV float lrelu(float z) { return z < 0.f ? 0.2f * z : z; }
DEV int clampi(int v, int hi) { return ((unsigned)v < (unsigned)hi) ? v : 0; }

// ---------------------------------------------------------------- dtype detect
__global__ void k_detect(const unsigned short* __restrict__ xw, int* __restrict__ flag) {
    int t = threadIdx.x;
    int cnt = 0;
    for (int i = t; i < 4096; i += 256) {
        int e = (xw[i] >> 7) & 0xFF;
        if (e >= 100 && e <= 140) cnt++;
    }
    __shared__ int sh[256];
    sh[t] = cnt;
    __syncthreads();
    for (int s = 128; s; s >>= 1) { if (t < s) sh[t] += sh[t + s]; __syncthreads(); }
    if (t == 0) *flag = (sh[0] >= 3300) ? 1 : 0;
}

// ---------------------------------------------------------------- convert params to f32
struct CvtDesc { const void* src; float* dst; int n; };
struct CvtArgs { CvtDesc d[25]; };
__global__ void k_convert(CvtArgs a, const int* __restrict__ flag) {
    CvtDesc dd = a.d[blockIdx.y];
    int i = blockIdx.x * 256 + threadIdx.x;
    if (i >= dd.n) return;
    float v = (*flag) ? __bfloat162float(((const bf16*)dd.src)[i])
                      : ((const float*)dd.src)[i];
    dd.dst[i] = v;
}

// ---------------------------------------------------------------- transpose (+ gn for grid, D=3)
DEV float rdval(const void* p, int i, int isbf) {
    return isbf ? __bfloat162float(((const bf16*)p)[i]) : ((const float*)p)[i];
}
__global__ void k_transpose(const void* __restrict__ x, const void* __restrict__ xg,
                            const int* __restrict__ flag,
                            float* __restrict__ xt, float* __restrict__ gt,
                            float* __restrict__ gT3, float* __restrict__ gn) {
    int isbf = *flag;
    int i = blockIdx.x * 256 + threadIdx.x;
    if (i < BN) {
        int b = i / N_, n = i % N_;
        for (int c = 0; c < 3; c++) xt[i * 3 + c] = rdval(x, (b * 3 + c) * N_ + n, isbf);
    }
    if (i < BM) {
        int b = i / M_, m = i % M_;
        float s = 0.f;
        for (int c = 0; c < 3; c++) {
            float v = rdval(xg, (b * 3 + c) * M_ + m, isbf);
            gt[i * 3 + c] = v;
            gT3[(b * 3 + c) * M_ + m] = v;
            s = fmaf(v, v, s);
        }
        gn[i] = s;
    }
}

// ---------------------------------------------------------------- fence-based deterministic finalize
// All blocks write partial[block][2*O] (fixed slots); last block (device-scope
// atomic counter) reduces in FIXED order with double accumulation -> prm.
template <int NP, int O>
DEV void fence_finalize(const float* __restrict__ partial, int* __restrict__ counter,
                        int C, const float* __restrict__ g, const float* __restrict__ bt,
                        float* __restrict__ prm) {
    __shared__ bool isLast;
    __threadfence();
    __syncthreads();
    if (threadIdx.x == 0) {
        int old = atomicAdd(counter, 1);
        isLast = (old == (int)gridDim.x - 1);
    }
    __syncthreads();
    if (!isLast) return;
    __threadfence();
    constexpr int VALS = 2 * O;
    __shared__ double sd[VALS];
    if constexpr (VALS <= 128) {
        constexpr int H = 256 / VALS;
        constexpr int SPAN = NP / H;
        __shared__ double hd[256];
        int v = threadIdx.x % VALS;
        int h = threadIdx.x / VALS;
        const float* p = partial + (size_t)h * SPAN * VALS + v;
        double s = 0.0;
#pragma unroll 32
        for (int k = 0; k < SPAN; k++) s += p[(size_t)k * VALS];
        hd[threadIdx.x] = s;
        __syncthreads();
        if (h == 0) {
            double tsum = hd[v];
            for (int j = 1; j < H; j++) tsum += hd[j * VALS + v];
            sd[v] = tsum;
        }
    } else {
        for (int v = threadIdx.x; v < VALS; v += 256) {
            const float* p = partial + v;
            double s = 0.0;
#pragma unroll 32
            for (int k = 0; k < NP; k++) s += p[(size_t)k * VALS];
            sd[v] = s;
        }
    }
    __syncthreads();
    for (int o = threadIdx.x; o < O; o += 256) {
        double m = sd[o] / C;
        double var = sd[O + o] / C - m * m;
        if (var < 0) var = 0;
        float sc = g[o] / sqrtf((float)var + EPS_);
        prm[o] = sc;
        prm[O + o] = bt[o] - (float)m * sc;
    }
}

// ---------------------------------------------------------------- nearest, D=3 (16 threads/point)
__global__ __launch_bounds__(256) void k_nearest3(const float* __restrict__ q,
                                                  const float* __restrict__ gt,
                                                  const float* __restrict__ gn,
                                                  int* __restrict__ nearest) {
    int sub = threadIdx.x & 15;
    int pt = blockIdx.x * 16 + (threadIdx.x >> 4);
    int b = pt >> 12;
    float q0 = q[pt * 3], q1 = q[pt * 3 + 1], q2 = q[pt * 3 + 2];
    float qn = q0 * q0 + q1 * q1 + q2 * q2;
    const float* gb = gt + (size_t)b * M_ * 3;
    const float* gnb = gn + b * M_;
    float best = 1e30f; int bi = 0x7fffffff;
    for (int j = 0; j < 32; j++) {
        int m = sub + 16 * j;
        float dot = q0 * gb[m * 3] + q1 * gb[m * 3 + 1] + q2 * gb[m * 3 + 2];
        float dv = qn + gnb[m] - 2.f * dot;
        if (dv < best || (dv == best && m < bi)) { best = dv; bi = m; }
    }
    for (int off = 8; off; off >>= 1) {
        float ov = __shfl_xor(best, off);
        int oi = __shfl_xor(bi, off);
        if (ov < best || (ov == best && oi < bi)) { best = ov; bi = oi; }
    }
    if (sub == 0) nearest[pt] = clampi(bi, M_);
}

// ---------------------------------------------------------------- nearest, D=64 (wave/point, m-vectorized)
__global__ __launch_bounds__(256) void k_nearest64(const float* __restrict__ q,
                                                   const float* __restrict__ gT,
                                                   const float* __restrict__ gn,
                                                   int* __restrict__ nearest) {
    int lane = threadIdx.x & 63;
    int pt = blockIdx.x * 4 + __builtin_amdgcn_readfirstlane(threadIdx.x >> 6);
    int b = pt >> 12;
    const float* qrow = q + (size_t)pt * 64;
    float qs[64];
#pragma unroll
    for (int c = 0; c < 64; c++) qs[c] = qrow[c];
    float qn = 0.f;
#pragma unroll
    for (int c = 0; c < 64; c++) qn = fmaf(qs[c], qs[c], qn);
    const float* gTb = gT + (size_t)b * 64 * M_;
    float d[8] = {0.f, 0.f, 0.f, 0.f, 0.f, 0.f, 0.f, 0.f};
#pragma unroll
    for (int c = 0; c < 64; c++) {
        float qc = qs[c];
        float4 g0 = *(const float4*)(gTb + c * M_ + 4 * lane);
        float4 g1 = *(const float4*)(gTb + c * M_ + 256 + 4 * lane);
        d[0] = fmaf(qc, g0.x, d[0]); d[1] = fmaf(qc, g0.y, d[1]);
        d[2] = fmaf(qc, g0.z, d[2]); d[3] = fmaf(qc, g0.w, d[3]);
        d[4] = fmaf(qc, g1.x, d[4]); d[5] = fmaf(qc, g1.y, d[5]);
        d[6] = fmaf(qc, g1.z, d[6]); d[7] = fmaf(qc, g1.w, d[7]);
    }
    const float* gnb = gn + b * M_;
    float4 n0 = *(const float4*)(gnb + 4 * lane);
    float4 n1 = *(const float4*)(gnb + 256 + 4 * lane);
    float nn[8] = {n0.x, n0.y, n0.z, n0.w, n1.x, n1.y, n1.z, n1.w};
    float best = 1e30f; int bi = 0;
#pragma unroll
    for (int i = 0; i < 8; i++) {
        int m = (i < 4) ? (4 * lane + i) : (256 + 4 * lane + i - 4);
        float dv = qn + nn[i] - 2.f * d[i];
        if (dv < best || (dv == best && m < bi)) { best = dv; bi = m; }
    }
    for (int off = 32; off; off >>= 1) {
        float ov = __shfl_xor(best, off);
        int oi = __shfl_xor(bi, off);
        if (ov < best || (ov == best && oi < bi)) { best = ov; bi = oi; }
    }
    if (lane == 0) nearest[pt] = clampi(bi, M_);
}

// ---------------------------------------------------------------- grid KNN + fused neighborhood stats
template <int D>
__global__ __launch_bounds__(256) void k_nbr2(
    const float* __restrict__ g, const float* __restrict__ gT,
    const float* __restrict__ gn, const float* __restrict__ Pg,
    int* __restrict__ nbr, float* __restrict__ T1, float* __restrict__ T2,
    float* __restrict__ Mn, float* __restrict__ Mx) {
    int lane = threadIdx.x & 63, w = threadIdx.x >> 6;
    int row = blockIdx.x * 4 + w;
    int b = row >> 9;
    const float* grow = g + (size_t)row * D;
    float qs[D];
#pragma unroll
    for (int c = 0; c < D; c++) qs[c] = grow[c];
    float qn = gn[row];
    const float* gTb = gT + (size_t)b * D * M_;
    const float* gnb = gn + b * M_;
    float d[8] = {0.f, 0.f, 0.f, 0.f, 0.f, 0.f, 0.f, 0.f};
#pragma unroll
    for (int c = 0; c < D; c++) {
        float qc = qs[c];
        float4 g0 = *(const float4*)(gTb + c * M_ + 4 * lane);
        float4 g1 = *(const float4*)(gTb + c * M_ + 256 + 4 * lane);
        d[0] = fmaf(qc, g0.x, d[0]); d[1] = fmaf(qc, g0.y, d[1]);
        d[2] = fmaf(qc, g0.z, d[2]); d[3] = fmaf(qc, g0.w, d[3]);
        d[4] = fmaf(qc, g1.x, d[4]); d[5] = fmaf(qc, g1.y, d[5]);
        d[6] = fmaf(qc, g1.z, d[6]); d[7] = fmaf(qc, g1.w, d[7]);
    }
    float4 n0 = *(const float4*)(gnb + 4 * lane);
    float4 n1 = *(const float4*)(gnb + 256 + 4 * lane);
    float dd[8];
    dd[0] = qn + n0.x - 2.f * d[0]; dd[1] = qn + n0.y - 2.f * d[1];
    dd[2] = qn + n0.z - 2.f * d[2]; dd[3] = qn + n0.w - 2.f * d[3];
    dd[4] = qn + n1.x - 2.f * d[4]; dd[5] = qn + n1.y - 2.f * d[5];
    dd[6] = qn + n1.z - 2.f * d[6]; dd[7] = qn + n1.w - 2.f * d[7];
    int mreg[8];
#pragma unroll
    for (int i = 0; i < 8; i++) mreg[i] = (i < 4) ? (4 * lane + i) : (256 + 4 * lane + i - 4);
    int myIdx = 0;
    for (int it = 0; it < K_; it++) {
        float bv = 1e30f; int bi = 0x7fffffff;
#pragma unroll
        for (int i = 0; i < 8; i++) {
            if (dd[i] < bv || (dd[i] == bv && mreg[i] < bi)) { bv = dd[i]; bi = mreg[i]; }
        }
        for (int off = 32; off; off >>= 1) {
            float ov = __shfl_xor(bv, off);
            int oi = __shfl_xor(bi, off);
            if (ov < bv || (ov == bv && oi < bi)) { bv = ov; bi = oi; }
        }
        bi = clampi(bi, M_);
        if (lane == it) { myIdx = bi; nbr[(size_t)row * K_ + it] = bi; }
#pragma unroll
        for (int i = 0; i < 8; i++) if (mreg[i] == bi) dd[i] = 1e30f;
    }
    const float* Pgb = Pg + (size_t)b * M_ * 64;
    float t1 = 0.f, t2 = 0.f, mn = 1e30f, mx = -1e30f;
#pragma unroll 7
    for (int k = 1; k < K_; k++) {
        int idx = __shfl(myIdx, k);
        float v = Pgb[(size_t)idx * 64 + lane];
        t1 += v; t2 = fmaf(v, v, t2);
        mn = fminf(mn, v); mx = fmaxf(mx, v);
    }
    size_t o = (size_t)row * 64 + lane;
    T1[o] = t1; T2[o] = t2; Mn[o] = mn; Mx[o] = mx;
}

// ---------------------------------------------------------------- deterministic block stats store
#define STATS_STORE_64(s1v, s2v, partial)                                         \
    {                                                                             \
        __shared__ float r1_[256], r2_[256];                                      \
        r1_[threadIdx.x] = (s1v); r2_[threadIdx.x] = (s2v);                       \
        __syncthreads();                                                          \
        if (threadIdx.x < 64) {                                                   \
            int t_ = threadIdx.x;                                                 \
            float a1_ = r1_[t_] + r1_[t_ + 64] + r1_[t_ + 128] + r1_[t_ + 192];   \
            float a2_ = r2_[t_] + r2_[t_ + 64] + r2_[t_ + 128] + r2_[t_ + 192];   \
            float* sp_ = (partial) + (size_t)blockIdx.x * 128;                    \
            sp_[t_] = a1_; sp_[64 + t_] = a2_;                                    \
        }                                                                         \
    }

// ---------------------------------------------------------------- Pg for stage A (D=3)
__global__ __launch_bounds__(256) void k_pgrid3(const float* __restrict__ g,
                                                const float* __restrict__ W1,
                                                float* __restrict__ Pg) {
    int lane = threadIdx.x & 63;
    int row = blockIdx.x * 4 + __builtin_amdgcn_readfirstlane(threadIdx.x >> 6);
    float c0 = g[row * 3], c1 = g[row * 3 + 1], c2 = g[row * 3 + 2];
    const float* wr = W1 + lane * 6;
    Pg[(size_t)row * 64 + lane] = fmaf(wr[0], c0, fmaf(wr[1], c1, wr[2] * c2));
}

// ---------------------------------------------------------------- fused grid prep (stages B/C)
__global__ __launch_bounds__(256) void k_gridprep(
    const float* __restrict__ xsrc, const int* __restrict__ FPS,
    const float* __restrict__ W1, float* __restrict__ xgt, float* __restrict__ gT,
    float* __restrict__ gn, float* __restrict__ Pg) {
    int lane = threadIdx.x & 63, w = threadIdx.x >> 6;
    int row = blockIdx.x * 4 + w;
    int b = row >> 9, m = row & 511;
    int src = b * N_ + clampi(FPS[row], N_);
    float ge = xsrc[(size_t)src * 64 + lane];
    xgt[(size_t)row * 64 + lane] = ge;
    gT[((size_t)b * 64 + lane) * M_ + m] = ge;
    const float* wr = W1 + lane * 128;
    float s = 0.f, acc = 0.f;
#pragma unroll
    for (int c = 0; c < 64; c++) {
        float vc = __shfl(ge, c);
        s = fmaf(vc, vc, s);
        acc = fmaf(wr[c], vc, acc);
    }
    Pg[(size_t)row * 64 + lane] = acc;
    if (lane == 0) gn[row] = s;
}

// ---------------------------------------------------------------- fused prep + BN stats (+inline finalize)
template <int D>
__global__ __launch_bounds__(256) void k_prep_stats(
    const float* __restrict__ q, const float* __restrict__ W1,
    const int* __restrict__ nearest, const float* __restrict__ T1,
    const float* __restrict__ T2, float* __restrict__ D0, float* __restrict__ S0,
    float* __restrict__ partial, int* __restrict__ counter, int C,
    const float* __restrict__ g, const float* __restrict__ bt, float* __restrict__ prm) {
    int lane = threadIdx.x & 63;
    int pt = blockIdx.x * 4 + __builtin_amdgcn_readfirstlane(threadIdx.x >> 6);
    int b = pt >> 12;
    float pa, pb;
    if constexpr (D == 3) {
        float c0 = q[pt * 3], c1 = q[pt * 3 + 1], c2 = q[pt * 3 + 2];
        const float* wr = W1 + lane * 6;
        pa = fmaf(wr[0], c0, fmaf(wr[1], c1, wr[2] * c2));
        pb = fmaf(wr[3], c0, fmaf(wr[4], c1, wr[5] * c2));
    } else {
        float ge = q[(size_t)pt * 64 + lane];
        const float* wr = W1 + lane * 128;
        pa = 0.f; pb = 0.f;
#pragma unroll
        for (int c = 0; c < 64; c++) {
            float sh = __shfl(ge, c);
            pa = fmaf(wr[c], sh, pa);
            pb = fmaf(wr[64 + c], sh, pb);
        }
    }
    float d0 = pb - pa, s0 = pb;
    size_t t = (size_t)pt * 64 + lane;
    D0[t] = d0;
    S0[t] = s0;
    size_t nr = ((size_t)b * M_ + clampi(nearest[pt], M_)) * 64 + lane;
    float t1 = T1[nr], t2 = T2[nr];
    float s1 = s0 + fmaf(49.f, d0, t1);
    float s2 = fmaf(s0, s0, fmaf(49.f * d0, d0, fmaf(2.f * d0, t1, t2)));
    STATS_STORE_64(s1, s2, partial)
    fence_finalize<2048, 64>(partial, counter, C, g, bt, prm);
}

// ---------------------------------------------------------------- stage-C output: bn+lrelu(max) exact
__global__ void k_apply0(const float* __restrict__ D0, const float* __restrict__ S0,
                         const int* __restrict__ nearest, const float* __restrict__ Mn,
                         const float* __restrict__ Mx, const float* __restrict__ prm,
                         float* __restrict__ xout) {
    int t = blockIdx.x * 256 + threadIdx.x;
    int pt = t >> 6, o = t & 63;
    int b = pt >> 12;
    size_t nr = ((size_t)b * M_ + clampi(nearest[pt], M_)) * 64 + o;
    float d0 = D0[t], s0 = S0[t];
    float a = prm[o], sh = prm[64 + o];
    float v = a > 0.f ? fmaxf(s0, d0 + Mx[nr]) : fminf(s0, d0 + Mn[nr]);
    xout[t] = lrelu(fmaf(a, v, sh));
}

// ---------------------------------------------------------------- pass1 (+inline finalize)
__global__ __launch_bounds__(256) void k_pass1(
    const float* __restrict__ Pg, const float* __restrict__ D0,
    const float* __restrict__ S0, const int* __restrict__ nearest,
    const int* __restrict__ nbr, const float* __restrict__ prm1,
    const float* __restrict__ W2, float* __restrict__ partial,
    float* __restrict__ mn_out, float* __restrict__ mx_out,
    int* __restrict__ counter, int C,
    const float* __restrict__ g, const float* __restrict__ bt,
    float* __restrict__ prm_out) {
    __shared__ float tile[4][64 * 17];
    __shared__ float ls1[256], ls2[256];
    int lane = threadIdx.x & 63;
    int wv = __builtin_amdgcn_readfirstlane(threadIdx.x >> 6);
    int pt = blockIdx.x * 4 + wv;
    int b = pt >> 12;
    int nr = clampi(nearest[pt], M_);
    const int* nrow = nbr + ((size_t)b * M_ + nr) * K_;
    int k = lane;
    int idx = (k >= 1 && k < K_) ? clampi(nrow[k], M_) : 0;
    const float4* src = (k == 0) ? (const float4*)(S0 + (size_t)pt * 64)
                                 : (const float4*)(Pg + ((size_t)b * M_ + idx) * 64);
    const float4* d0r = (const float4*)(D0 + (size_t)pt * 64);
    const float4* a4 = (const float4*)(prm1);
    const float4* s4 = (const float4*)(prm1 + 64);
    float dscale = (k == 0) ? 0.f : 1.f;
    float z[64];
#pragma unroll
    for (int c4 = 0; c4 < 16; c4++) {
        float4 v = src[c4]; float4 d = d0r[c4]; float4 a = a4[c4]; float4 s = s4[c4];
        z[4 * c4 + 0] = lrelu(fmaf(a.x, fmaf(dscale, d.x, v.x), s.x));
        z[4 * c4 + 1] = lrelu(fmaf(a.y, fmaf(dscale, d.y, v.y), s.y));
        z[4 * c4 + 2] = lrelu(fmaf(a.z, fmaf(dscale, d.z, v.z), s.z));
        z[4 * c4 + 3] = lrelu(fmaf(a.w, fmaf(dscale, d.w, v.w), s.w));
    }
    float* tl = tile[wv];
    int o_l = lane & 15, kg = lane >> 4;
#pragma clang loop unroll(disable)
    for (int ch = 0; ch < 4; ch++) {
#pragma clang loop unroll(disable)
        for (int og = 0; og < 4; og++) {
            int obase = ch * 16 + og * 4;
            const float4* wr0 = (const float4*)(W2 + (obase + 0) * 64);
            const float4* wr1 = (const float4*)(W2 + (obase + 1) * 64);
            const float4* wr2 = (const float4*)(W2 + (obase + 2) * 64);
            const float4* wr3 = (const float4*)(W2 + (obase + 3) * 64);
            float a0 = 0.f, a1 = 0.f, a2 = 0.f, a3 = 0.f;
#pragma unroll
            for (int c4 = 0; c4 < 16; c4++) {
                float z0 = z[4 * c4 + 0], z1 = z[4 * c4 + 1];
                float z2 = z[4 * c4 + 2], z3 = z[4 * c4 + 3];
                float4 w0 = wr0[c4], w1 = wr1[c4], w2 = wr2[c4], w3 = wr3[c4];
                a0 = fmaf(w0.x, z0, a0); a0 = fmaf(w0.y, z1, a0);
                a0 = fmaf(w0.z, z2, a0); a0 = fmaf(w0.w, z3, a0);
                a1 = fmaf(w1.x, z0, a1); a1 = fmaf(w1.y, z1, a1);
                a1 = fmaf(w1.z, z2, a1); a1 = fmaf(w1.w, z3, a1);
                a2 = fmaf(w2.x, z0, a2); a2 = fmaf(w2.y, z1, a2);
                a2 = fmaf(w2.z, z2, a2); a2 = fmaf(w2.w, z3, a2);
                a3 = fmaf(w3.x, z0, a3); a3 = fmaf(w3.y, z1, a3);
                a3 = fmaf(w3.z, z2, a3); a3 = fmaf(w3.w, z3, a3);
            }
            tl[lane * 17 + og * 4 + 0] = a0;
            tl[lane * 17 + og * 4 + 1] = a1;
            tl[lane * 17 + og * 4 + 2] = a2;
            tl[lane * 17 + og * 4 + 3] = a3;
        }
        float p1 = 0.f, p2 = 0.f, pm = -1e30f, pn = 1e30f;
#pragma unroll
        for (int i = 0; i < 16; i++) {
            int kk = kg * 16 + i;
            if (kk < K_) {
                float v = tl[kk * 17 + o_l];
                p1 += v; p2 = fmaf(v, v, p2);
                pm = fmaxf(pm, v); pn = fminf(pn, v);
            }
        }
        p1 += __shfl_xor(p1, 16); p1 += __shfl_xor(p1, 32);
        p2 += __shfl_xor(p2, 16); p2 += __shfl_xor(p2, 32);
        pm = fmaxf(pm, __shfl_xor(pm, 16)); pm = fmaxf(pm, __shfl_xor(pm, 32));
        pn = fminf(pn, __shfl_xor(pn, 16)); pn = fminf(pn, __shfl_xor(pn, 32));
        if (lane < 16) {
            int o = ch * 16 + lane;
            mn_out[(size_t)pt * 64 + o] = pn;
            mx_out[(size_t)pt * 64 + o] = pm;
            ls1[wv * 64 + o] = p1;
            ls2[wv * 64 + o] = p2;
        }
    }
    __syncthreads();
    if (threadIdx.x < 64) {
        int t = threadIdx.x;
        float a1 = ls1[t] + ls1[64 + t] + ls1[128 + t] + ls1[192 + t];
        float a2 = ls2[t] + ls2[64 + t] + ls2[128 + t] + ls2[192 + t];
        float* sp = partial + (size_t)blockIdx.x * 128;
        sp[t] = a1; sp[64 + t] = a2;
    }
    fence_finalize<2048, 64>(partial, counter, C, g, bt, prm_out);
}

// ---------------------------------------------------------------- apply bn+lrelu to min/max (exact)
__global__ void k_apply(const float* __restrict__ mn, const float* __restrict__ mx,
                        const float* __restrict__ prm, float* __restrict__ xout) {
    int t = blockIdx.x * 256 + threadIdx.x;
    int o = t & 63;
    float a = prm[o], sh = prm[64 + o];
    float v = a > 0.f ? mx[t] : mn[t];
    xout[t] = lrelu(fmaf(a, v, sh));
}

// ---------------------------------------------------------------- W6 conv (192->512), x3 gathered; +finalize
__global__ __launch_bounds__(256) void k_conv_w6(
    const float* __restrict__ x1gt, const float* __restrict__ x2gt,
    const float* __restrict__ x3t, const int* __restrict__ FPS,
    const float* __restrict__ W6, float* __restrict__ y6, float* __restrict__ partial,
    int* __restrict__ counter, int C,
    const float* __restrict__ g, const float* __restrict__ bt, float* __restrict__ prm) {
    __shared__ float vl[8][192];
    int b = blockIdx.x / (M_ / 8);
    int m0 = (blockIdx.x % (M_ / 8)) * 8;
    for (int i = threadIdx.x; i < 8 * 192; i += 256) {
        int mi = i / 192, c = i % 192;
        float v;
        if (c < 128) {
            const float* src = c < 64 ? x1gt : x2gt;
            v = src[((size_t)b * M_ + m0 + mi) * 64 + (c & 63)];
        } else {
            int src = b * N_ + clampi(FPS[b * M_ + m0 + mi], N_);
            v = x3t[(size_t)src * 64 + (c - 128)];
        }
        vl[mi][c] = v;
    }
    __syncthreads();
    float acc0[8] = {0}, acc1[8] = {0};
    int o0 = threadIdx.x, o1 = threadIdx.x + 256;
    for (int c = 0; c < 192; c++) {
        float w0 = W6[o0 * 192 + c];
        float w1 = W6[o1 * 192 + c];
#pragma unroll
        for (int m = 0; m < 8; m++) { float v = vl[m][c]; acc0[m] = fmaf(w0, v, acc0[m]); acc1[m] = fmaf(w1, v, acc1[m]); }
    }
    float s1a = 0, s2a = 0, s1b = 0, s2b = 0;
    for (int m = 0; m < 8; m++) {
        float ya = acc0[m], yb = acc1[m];
        y6[((size_t)b * M_ + m0 + m) * 512 + o0] = ya;
        y6[((size_t)b * M_ + m0 + m) * 512 + o1] = yb;
        s1a += ya; s2a = fmaf(ya, ya, s2a); s1b += yb; s2b = fmaf(yb, yb, s2b);
    }
    float* sp = partial + (size_t)blockIdx.x * 1024;
    sp[o0] = s1a; sp[512 + o0] = s2a;
    sp[o1] = s1b; sp[512 + o1] = s2b;
    fence_finalize<128, 512>(partial, counter, C, g, bt, prm);
}

// ---------------------------------------------------------------- bn6+lrelu+max over M
__global__ void k_maxM(const float* __restrict__ y6, const float* __restrict__ prm,
                       float* __restrict__ xgmax) {
    int blk = blockIdx.x;
    int b = blk >> 4;
    int o = ((blk & 15) << 5) + (threadIdx.x & 31);
    int mg = threadIdx.x >> 5;
    float a = prm[o], sh = prm[512 + o];
    float mx = -1e30f;
    for (int m = mg; m < M_; m += 8)
        mx = fmaxf(mx, lrelu(fmaf(a, y6[((size_t)b * M_ + m) * 512 + o], sh)));
    __shared__ float red[256];
    red[threadIdx.x] = mx;
    __syncthreads();
    for (int s = 128; s >= 32; s >>= 1) {
        if (threadIdx.x < s) red[threadIdx.x] = fmaxf(red[threadIdx.x], red[threadIdx.x + s]);
        __syncthreads();
    }
    if (threadIdx.x < 32) xgmax[b * 512 + o] = red[threadIdx.x];
}

// ---------------------------------------------------------------- P7: wave per output (fixed xor tree)
__global__ __launch_bounds__(256) void k_p7(const float* __restrict__ xgmax,
                                            const float* __restrict__ W7,
                                            float* __restrict__ p7) {
    int lane = threadIdx.x & 63, w = threadIdx.x >> 6;
    int t = blockIdx.x * 4 + w;     // 0..255
    int b = t >> 7, o = t & 127;
    float acc = 0.f;
#pragma unroll
    for (int j = 0; j < 8; j++) {
        int c = j * 64 + lane;
        acc = fmaf(W7[o * 704 + c], xgmax[b * 512 + c], acc);
    }
    for (int off = 32; off; off >>= 1) acc += __shfl_xor(acc, off);
    if (lane == 0) p7[t] = acc;
}

// ---------------------------------------------------------------- W7 conv (704->128); +finalize
__global__ __launch_bounds__(256) void k_conv_w7(
    const float* __restrict__ x1t, const float* __restrict__ x2t,
    const float* __restrict__ x3t, const float* __restrict__ p7,
    const float* __restrict__ W7, float* __restrict__ y7, float* __restrict__ partial,
    int* __restrict__ counter, int C,
    const float* __restrict__ g, const float* __restrict__ bt, float* __restrict__ prm) {
    __shared__ float vl[16][192];
    int item0 = blockIdx.x * 16;
    for (int i = threadIdx.x; i < 16 * 192; i += 256) {
        int it = i / 192, c = i % 192;
        const float* src = c < 64 ? x1t : (c < 128 ? x2t : x3t);
        vl[it][c] = src[((size_t)(item0 + it)) * 64 + (c & 63)];
    }
    __syncthreads();
    int o = threadIdx.x & 127, h = threadIdx.x >> 7;
    float acc[8] = {0};
    for (int c = 0; c < 192; c++) {
        float w = W7[o * 704 + 512 + c];
#pragma unroll
        for (int i = 0; i < 8; i++) acc[i] = fmaf(w, vl[h * 8 + i][c], acc[i]);
    }
    float s1 = 0, s2 = 0;
    for (int i = 0; i < 8; i++) {
        int item = item0 + h * 8 + i;
        int b = item / N_;
        float yv = p7[b * 128 + o] + acc[i];
        y7[(size_t)item * 128 + o] = yv;
        s1 += yv; s2 = fmaf(yv, yv, s2);
    }
    __shared__ float r1[256], r2[256];
    r1[threadIdx.x] = s1; r2[threadIdx.x] = s2;
    __syncthreads();
    if (threadIdx.x < 128) {
        float* sp = partial + (size_t)blockIdx.x * 256;
        sp[threadIdx.x] = r1[threadIdx.x] + r1[threadIdx.x + 128];
        sp[128 + threadIdx.x] = r2[threadIdx.x] + r2[threadIdx.x + 128];
    }
    fence_finalize<512, 128>(partial, counter, C, g, bt, prm);
}

// ---------------------------------------------------------------- W8 conv (128->64); +finalize
__global__ __launch_bounds__(256) void k_conv_w8(
    const float* __restrict__ y7, const float* __restrict__ prm7,
    const float* __restrict__ W8, float* __restrict__ y8, float* __restrict__ partial,
    int* __restrict__ counter, int C,
    const float* __restrict__ g, const float* __restrict__ bt, float* __restrict__ prm) {
    int lane = threadIdx.x & 63;
    int item = blockIdx.x * 4 + (threadIdx.x >> 6);
    float W0[64], W1r[64];
#pragma unroll
    for (int c = 0; c < 64; c++) {
        W0[c] = W8[lane * 128 + c];
        W1r[c] = W8[lane * 128 + 64 + c];
    }
    float a0 = prm7[lane], sh0 = prm7[128 + lane];
    float a1 = prm7[64 + lane], sh1 = prm7[128 + 64 + lane];
    float z0 = lrelu(fmaf(a0, y7[(size_t)item * 128 + lane], sh0));
    float z1 = lrelu(fmaf(a1, y7[(size_t)item * 128 + 64 + lane], sh1));
    float acc = 0.f;
#pragma unroll
    for (int c = 0; c < 64; c++) {
        acc = fmaf(W0[c], __shfl(z0, c), acc);
        acc = fmaf(W1r[c], __shfl(z1, c), acc);
    }
    y8[(size_t)item * 64 + lane] = acc;
    STATS_STORE_64(acc, acc * acc, partial)
    fence_finalize<2048, 64>(partial, counter, C, g, bt, prm);
}

// ---------------------------------------------------------------- final: bn8+lrelu, W9 -> out
__global__ __launch_bounds__(256) void k_final(
    const float* __restrict__ y8, const float* __restrict__ prm8,
    const float* __restrict__ W9, void* __restrict__ out, const int* __restrict__ flag) {
    __shared__ float zl[2][64];
    int item0 = blockIdx.x * 2;
    if (threadIdx.x < 128) {
        int it = threadIdx.x >> 6, c = threadIdx.x & 63;
        float z = fmaf(prm8[c], y8[(size_t)(item0 + it) * 64 + c], prm8[64 + c]);
        zl[it][c] = lrelu(z);
    }
    __syncthreads();
    int it = threadIdx.x >> 7, o = threadIdx.x & 127;
    float acc = 0.f;
#pragma unroll
    for (int c = 0; c < 64; c++) acc = fmaf(W9[o * 64 + c], zl[it][c], acc);
    size_t oi = (size_t)(item0 + it) * 128 + o;
    if (*flag) ((bf16*)out)[oi] = __float2bfloat16(acc);
    else ((float*)out)[oi] = acc;
}

// ---------------------------------------------------------------- host
extern "C" void kernel_launch(void* const* d_in, const int* in_sizes, int n_in,
                              void* d_out, int out_size, void* d_ws, size_t ws_size,
                              hipStream_t stream) {
    (void)in_sizes; (void)n_in; (void)out_size; (void)ws_size;
    const void* x = d_in[0];
    const void* xgrid = d_in[1];
    const int* FPS = (const int*)d_in[2];

    char* ws = (char*)d_ws;
    size_t off = 0;
    auto alloc = [&](size_t bytes) -> char* {
        char* p = ws + off;
        off = (off + bytes + 255) & ~(size_t)255;
        return p;
    };
    int* flag       = (int*)alloc(256);
    int* counters   = (int*)alloc(256);                            // 8 fence counters
    float* partials = (float*)alloc(2048 * 128 * sizeof(float));   // 1 MB, per-block stats slots
    float* prm      = (float*)alloc(8 * 1024 * sizeof(float));
    static const int wsz[9] = {384, 4096, 8192, 4096, 8192, 98304, 90112, 8192, 8192};
    static const int dims[8] = {64, 64, 64, 64, 64, 512, 128, 64};
    float* cW[9];
    for (int i = 0; i < 9; i++) cW[i] = (float*)alloc((size_t)wsz[i] * 4);
    float* cG[8];
    float* cB[8];
    for (int j = 0; j < 8; j++) {
        cG[j] = (float*)alloc((size_t)dims[j] * 4);
        cB[j] = (float*)alloc((size_t)dims[j] * 4);
    }
    float* xt    = (float*)alloc((size_t)BN * 3 * 4);
    float* gt    = (float*)alloc((size_t)BM * 3 * 4);
    float* gT3   = (float*)alloc((size_t)B_ * 3 * M_ * 4);
    float* gn    = (float*)alloc((size_t)BM * 4);
    int* nearest = (int*)alloc((size_t)BN * 4);
    int* nbr     = (int*)alloc((size_t)BM * K_ * 4);
    float* Pg    = (float*)alloc((size_t)BM * 64 * 4);
    float* x1t   = (float*)alloc((size_t)BN * 64 * 4);
    float* x2t   = (float*)alloc((size_t)BN * 64 * 4);
    float* x3t   = (float*)alloc((size_t)BN * 64 * 4);
    float* x1gt  = (float*)alloc((size_t)BM * 64 * 4);
    float* x2gt  = (float*)alloc((size_t)BM * 64 * 4);
    float* gT64  = (float*)alloc((size_t)B_ * 64 * M_ * 4);
    float* y6    = (float*)alloc((size_t)BM * 512 * 4);    // 2 MB
    float* xgmax = (float*)alloc((size_t)B_ * 512 * 4);
    float* p7    = (float*)alloc((size_t)B_ * 128 * 4);
    float* y7    = (float*)alloc((size_t)BN * 128 * 4);    // 4 MB
    float* y8    = (float*)alloc((size_t)BN * 64 * 4);     // 2 MB
    // Aliases (lifetimes verified; same layout as passing rounds):
    float* D0b = y7;
    float* S0b = y7 + (size_t)BN * 64;
    float* mnb = y8;
    float* mxb = y6;
    float* T1b = y6;
    float* T2b = y6 + (size_t)BM * 64;
    float* Mnb = y6 + (size_t)2 * BM * 64;
    float* Mxb = y6 + (size_t)3 * BM * 64;

    hipMemsetAsync(counters, 0, 8 * sizeof(int), stream);
    k_detect<<<1, 256, 0, stream>>>((const unsigned short*)x, flag);

    CvtArgs ca;
    for (int i = 0; i < 9; i++) ca.d[i] = {d_in[3 + i], cW[i], wsz[i]};
    for (int j = 0; j < 8; j++) {
        ca.d[9 + 2 * j]     = {d_in[12 + 2 * j], cG[j], dims[j]};
        ca.d[9 + 2 * j + 1] = {d_in[13 + 2 * j], cB[j], dims[j]};
    }
    k_convert<<<dim3(384, 25), 256, 0, stream>>>(ca, flag);
    k_transpose<<<(BN + 255) / 256, 256, 0, stream>>>(x, xgrid, flag, xt, gt, gT3, gn);

    const int PG = BN / 4;         // wave-per-point grids (2048)
    const int EW = BN * 64 / 256;  // elementwise grids
    const int CK = BN * K_;

    // ---- stage A (D=3, W1,W2) ----
    k_pgrid3<<<BM / 4, 256, 0, stream>>>(gt, cW[0], Pg);
    k_nearest3<<<BN / 16, 256, 0, stream>>>(xt, gt, gn, nearest);
    k_nbr2<3><<<BM / 4, 256, 0, stream>>>(gt, gT3, gn, Pg, nbr, T1b, T2b, Mnb, Mxb);
    k_prep_stats<3><<<PG, 256, 0, stream>>>(xt, cW[0], nearest, T1b, T2b, D0b, S0b,
                                            partials, counters + 0, CK, cG[0], cB[0], prm + 0 * 1024);
    k_pass1<<<PG, 256, 0, stream>>>(Pg, D0b, S0b, nearest, nbr, prm + 0 * 1024, cW[1],
                                    partials, mnb, mxb, counters + 1, CK, cG[1], cB[1], prm + 1 * 1024);
    k_apply<<<EW, 256, 0, stream>>>(mnb, mxb, prm + 1 * 1024, x1t);

    // ---- stage B (D=64, W3,W4) ----
    k_gridprep<<<BM / 4, 256, 0, stream>>>(x1t, FPS, cW[2], x1gt, gT64, gn, Pg);
    k_nearest64<<<PG, 256, 0, stream>>>(x1t, gT64, gn, nearest);
    k_nbr2<64><<<BM / 4, 256, 0, stream>>>(x1gt, gT64, gn, Pg, nbr, T1b, T2b, Mnb, Mxb);
    k_prep_stats<64><<<PG, 256, 0, stream>>>(x1t, cW[2], nearest, T1b, T2b, D0b, S0b,
                                             partials, counters + 2, CK, cG[2], cB[2], prm + 2 * 1024);
    k_pass1<<<PG, 256, 0, stream>>>(Pg, D0b, S0b, nearest, nbr, prm + 2 * 1024, cW[3],
                                    partials, mnb, mxb, counters + 3, CK, cG[3], cB[3], prm + 3 * 1024);
    k_apply<<<EW, 256, 0, stream>>>(mnb, mxb, prm + 3 * 1024, x2t);

    // ---- stage C (D=64, W5 single conv) ----
    k_gridprep<<<BM / 4, 256, 0, stream>>>(x2t, FPS, cW[4], x2gt, gT64, gn, Pg);
    k_nearest64<<<PG, 256, 0, stream>>>(x2t, gT64, gn, nearest);
    k_nbr2<64><<<BM / 4, 256, 0, stream>>>(x2gt, gT64, gn, Pg, nbr, T1b, T2b, Mnb, Mxb);
    k_prep_stats<64><<<PG, 256, 0, stream>>>(x2t, cW[4], nearest, T1b, T2b, D0b, S0b,
                                             partials, counters + 4, CK, cG[4], cB[4], prm + 4 * 1024);
    k_apply0<<<EW, 256, 0, stream>>>(D0b, S0b, nearest, Mnb, Mxb, prm + 4 * 1024, x3t);

    // ---- global MLP tail (x3 gather fused into k_conv_w6) ----
    k_conv_w6<<<BM / 8, 256, 0, stream>>>(x1gt, x2gt, x3t, FPS, cW[5], y6,
                                          partials, counters + 5, BM, cG[5], cB[5], prm + 5 * 1024);
    k_maxM<<<B_ * 16, 256, 0, stream>>>(y6, prm + 5 * 1024, xgmax);
    k_p7<<<64, 256, 0, stream>>>(xgmax, cW[6], p7);
    k_conv_w7<<<BN / 16, 256, 0, stream>>>(x1t, x2t, x3t, p7, cW[6], y7,
                                           partials, counters + 6, BN, cG[6], cB[6], prm + 6 * 1024);
    k_conv_w8<<<BN / 4, 256, 0, stream>>>(y7, prm + 6 * 1024, cW[7], y8,
                                          partials, counters + 7, BN, cG[7], cB[7], prm + 7 * 1024);
    k_final<<<BN / 2, 256, 0, stream>>>(y8, prm + 7 * 1024, cW[8], d_out, flag);
}

// Round 11
// 888.109 us; speedup vs baseline: 2.0724x; 2.0724x over previous
//
#include <hip/hip_runtime.h>
#include <hip/hip_bf16.h>

#define DEV __device__ __forceinline__
using bf16 = __hip_bfloat16;

static constexpr int B_ = 2, N_ = 4096, M_ = 512, K_ = 50;
static constexpr int BN = B_ * N_;   // 8192 points
static constexpr int BM = B_ * M_;   // 1024 grid points
static constexpr float EPS_ = 1e-5f;

DEV float lrelu(float z) { return z < 0.f ? 0.2f * z : z; }
DEV int clampi(int v, int hi) { return ((unsigned)v < (unsigned)hi) ? v : 0; }

// ---------------------------------------------------------------- dtype detect
__global__ void k_detect(const unsigned short* __restrict__ xw, int* __restrict__ flag) {
    int t = threadIdx.x;
    int cnt = 0;
    for (int i = t; i < 4096; i += 256) {
        int e = (xw[i] >> 7) & 0xFF;
        if (e >= 100 && e <= 140) cnt++;
    }
    __shared__ int sh[256];
    sh[t] = cnt;
    __syncthreads();
    for (int s = 128; s; s >>= 1) { if (t < s) sh[t] += sh[t + s]; __syncthreads(); }
    if (t == 0) *flag = (sh[0] >= 3300) ? 1 : 0;
}

// ---------------------------------------------------------------- convert params to f32
struct CvtDesc { const void* src; float* dst; int n; };
struct CvtArgs { CvtDesc d[25]; };
__global__ void k_convert(CvtArgs a, const int* __restrict__ flag) {
    CvtDesc dd = a.d[blockIdx.y];
    int i = blockIdx.x * 256 + threadIdx.x;
    if (i >= dd.n) return;
    float v = (*flag) ? __bfloat162float(((const bf16*)dd.src)[i])
                      : ((const float*)dd.src)[i];
    dd.dst[i] = v;
}

// ---------------------------------------------------------------- transpose (+ gn for grid, D=3)
DEV float rdval(const void* p, int i, int isbf) {
    return isbf ? __bfloat162float(((const bf16*)p)[i]) : ((const float*)p)[i];
}
__global__ void k_transpose(const void* __restrict__ x, const void* __restrict__ xg,
                            const int* __restrict__ flag,
                            float* __restrict__ xt, float* __restrict__ gt,
                            float* __restrict__ gT3, float* __restrict__ gn) {
    int isbf = *flag;
    int i = blockIdx.x * 256 + threadIdx.x;
    if (i < BN) {
        int b = i / N_, n = i % N_;
        for (int c = 0; c < 3; c++) xt[i * 3 + c] = rdval(x, (b * 3 + c) * N_ + n, isbf);
    }
    if (i < BM) {
        int b = i / M_, m = i % M_;
        float s = 0.f;
        for (int c = 0; c < 3; c++) {
            float v = rdval(xg, (b * 3 + c) * M_ + m, isbf);
            gt[i * 3 + c] = v;
            gT3[(b * 3 + c) * M_ + m] = v;
            s = fmaf(v, v, s);
        }
        gn[i] = s;
    }
}

// ---------------------------------------------------------------- nearest, D=3 (16 threads/point)
__global__ __launch_bounds__(256) void k_nearest3(const float* __restrict__ q,
                                                  const float* __restrict__ gt,
                                                  const float* __restrict__ gn,
                                                  int* __restrict__ nearest) {
    int sub = threadIdx.x & 15;
    int pt = blockIdx.x * 16 + (threadIdx.x >> 4);
    int b = pt >> 12;
    float q0 = q[pt * 3], q1 = q[pt * 3 + 1], q2 = q[pt * 3 + 2];
    float qn = q0 * q0 + q1 * q1 + q2 * q2;
    const float* gb = gt + (size_t)b * M_ * 3;
    const float* gnb = gn + b * M_;
    float best = 1e30f; int bi = 0x7fffffff;
    for (int j = 0; j < 32; j++) {
        int m = sub + 16 * j;
        float dot = q0 * gb[m * 3] + q1 * gb[m * 3 + 1] + q2 * gb[m * 3 + 2];
        float dv = qn + gnb[m] - 2.f * dot;
        if (dv < best || (dv == best && m < bi)) { best = dv; bi = m; }
    }
    for (int off = 8; off; off >>= 1) {
        float ov = __shfl_xor(best, off);
        int oi = __shfl_xor(bi, off);
        if (ov < best || (ov == best && oi < bi)) { best = ov; bi = oi; }
    }
    if (sub == 0) nearest[pt] = clampi(bi, M_);
}

// ---------------------------------------------------------------- nearest, D=64 (wave/point, m-vectorized)
__global__ __launch_bounds__(256) void k_nearest64(const float* __restrict__ q,
                                                   const float* __restrict__ gT,
                                                   const float* __restrict__ gn,
                                                   int* __restrict__ nearest) {
    int lane = threadIdx.x & 63;
    int pt = blockIdx.x * 4 + __builtin_amdgcn_readfirstlane(threadIdx.x >> 6);
    int b = pt >> 12;
    const float* qrow = q + (size_t)pt * 64;
    float qs[64];
#pragma unroll
    for (int c = 0; c < 64; c++) qs[c] = qrow[c];
    float qn = 0.f;
#pragma unroll
    for (int c = 0; c < 64; c++) qn = fmaf(qs[c], qs[c], qn);
    const float* gTb = gT + (size_t)b * 64 * M_;
    float d[8] = {0.f, 0.f, 0.f, 0.f, 0.f, 0.f, 0.f, 0.f};
#pragma unroll
    for (int c = 0; c < 64; c++) {
        float qc = qs[c];
        float4 g0 = *(const float4*)(gTb + c * M_ + 4 * lane);
        float4 g1 = *(const float4*)(gTb + c * M_ + 256 + 4 * lane);
        d[0] = fmaf(qc, g0.x, d[0]); d[1] = fmaf(qc, g0.y, d[1]);
        d[2] = fmaf(qc, g0.z, d[2]); d[3] = fmaf(qc, g0.w, d[3]);
        d[4] = fmaf(qc, g1.x, d[4]); d[5] = fmaf(qc, g1.y, d[5]);
        d[6] = fmaf(qc, g1.z, d[6]); d[7] = fmaf(qc, g1.w, d[7]);
    }
    const float* gnb = gn + b * M_;
    float4 n0 = *(const float4*)(gnb + 4 * lane);
    float4 n1 = *(const float4*)(gnb + 256 + 4 * lane);
    float nn[8] = {n0.x, n0.y, n0.z, n0.w, n1.x, n1.y, n1.z, n1.w};
    float best = 1e30f; int bi = 0;
#pragma unroll
    for (int i = 0; i < 8; i++) {
        int m = (i < 4) ? (4 * lane + i) : (256 + 4 * lane + i - 4);
        float dv = qn + nn[i] - 2.f * d[i];
        if (dv < best || (dv == best && m < bi)) { best = dv; bi = m; }
    }
    for (int off = 32; off; off >>= 1) {
        float ov = __shfl_xor(best, off);
        int oi = __shfl_xor(bi, off);
        if (ov < best || (ov == best && oi < bi)) { best = ov; bi = oi; }
    }
    if (lane == 0) nearest[pt] = clampi(bi, M_);
}

// ---------------------------------------------------------------- grid KNN + fused neighborhood stats
template <int D>
__global__ __launch_bounds__(256) void k_nbr2(
    const float* __restrict__ g, const float* __restrict__ gT,
    const float* __restrict__ gn, const float* __restrict__ Pg,
    int* __restrict__ nbr, float* __restrict__ T1, float* __restrict__ T2,
    float* __restrict__ Mn, float* __restrict__ Mx) {
    int lane = threadIdx.x & 63, w = threadIdx.x >> 6;
    int row = blockIdx.x * 4 + w;
    int b = row >> 9;
    const float* grow = g + (size_t)row * D;
    float qs[D];
#pragma unroll
    for (int c = 0; c < D; c++) qs[c] = grow[c];
    float qn = gn[row];
    const float* gTb = gT + (size_t)b * D * M_;
    const float* gnb = gn + b * M_;
    float d[8] = {0.f, 0.f, 0.f, 0.f, 0.f, 0.f, 0.f, 0.f};
#pragma unroll
    for (int c = 0; c < D; c++) {
        float qc = qs[c];
        float4 g0 = *(const float4*)(gTb + c * M_ + 4 * lane);
        float4 g1 = *(const float4*)(gTb + c * M_ + 256 + 4 * lane);
        d[0] = fmaf(qc, g0.x, d[0]); d[1] = fmaf(qc, g0.y, d[1]);
        d[2] = fmaf(qc, g0.z, d[2]); d[3] = fmaf(qc, g0.w, d[3]);
        d[4] = fmaf(qc, g1.x, d[4]); d[5] = fmaf(qc, g1.y, d[5]);
        d[6] = fmaf(qc, g1.z, d[6]); d[7] = fmaf(qc, g1.w, d[7]);
    }
    float4 n0 = *(const float4*)(gnb + 4 * lane);
    float4 n1 = *(const float4*)(gnb + 256 + 4 * lane);
    float dd[8];
    dd[0] = qn + n0.x - 2.f * d[0]; dd[1] = qn + n0.y - 2.f * d[1];
    dd[2] = qn + n0.z - 2.f * d[2]; dd[3] = qn + n0.w - 2.f * d[3];
    dd[4] = qn + n1.x - 2.f * d[4]; dd[5] = qn + n1.y - 2.f * d[5];
    dd[6] = qn + n1.z - 2.f * d[6]; dd[7] = qn + n1.w - 2.f * d[7];
    int mreg[8];
#pragma unroll
    for (int i = 0; i < 8; i++) mreg[i] = (i < 4) ? (4 * lane + i) : (256 + 4 * lane + i - 4);
    int myIdx = 0;
    for (int it = 0; it < K_; it++) {
        float bv = 1e30f; int bi = 0x7fffffff;
#pragma unroll
        for (int i = 0; i < 8; i++) {
            if (dd[i] < bv || (dd[i] == bv && mreg[i] < bi)) { bv = dd[i]; bi = mreg[i]; }
        }
        for (int off = 32; off; off >>= 1) {
            float ov = __shfl_xor(bv, off);
            int oi = __shfl_xor(bi, off);
            if (ov < bv || (ov == bv && oi < bi)) { bv = ov; bi = oi; }
        }
        bi = clampi(bi, M_);
        if (lane == it) { myIdx = bi; nbr[(size_t)row * K_ + it] = bi; }
#pragma unroll
        for (int i = 0; i < 8; i++) if (mreg[i] == bi) dd[i] = 1e30f;
    }
    const float* Pgb = Pg + (size_t)b * M_ * 64;
    float t1 = 0.f, t2 = 0.f, mn = 1e30f, mx = -1e30f;
#pragma unroll 7
    for (int k = 1; k < K_; k++) {
        int idx = __shfl(myIdx, k);
        float v = Pgb[(size_t)idx * 64 + lane];
        t1 += v; t2 = fmaf(v, v, t2);
        mn = fminf(mn, v); mx = fmaxf(mx, v);
    }
    size_t o = (size_t)row * 64 + lane;
    T1[o] = t1; T2[o] = t2; Mn[o] = mn; Mx[o] = mx;
}

// ---------------------------------------------------------------- deterministic block stats store
#define STATS_STORE_64(s1v, s2v, partial)                                         \
    {                                                                             \
        __shared__ float r1_[256], r2_[256];                                      \
        r1_[threadIdx.x] = (s1v); r2_[threadIdx.x] = (s2v);                       \
        __syncthreads();                                                          \
        if (threadIdx.x < 64) {                                                   \
            int t_ = threadIdx.x;                                                 \
            float a1_ = r1_[t_] + r1_[t_ + 64] + r1_[t_ + 128] + r1_[t_ + 192];   \
            float a2_ = r2_[t_] + r2_[t_ + 64] + r2_[t_ + 128] + r2_[t_ + 192];   \
            float* sp_ = (partial) + (size_t)blockIdx.x * 128;                    \
            sp_[t_] = a1_; sp_[64 + t_] = a2_;                                    \
        }                                                                         \
    }

// ---------------------------------------------------------------- Pg for stage A (D=3)
__global__ __launch_bounds__(256) void k_pgrid3(const float* __restrict__ g,
                                                const float* __restrict__ W1,
                                                float* __restrict__ Pg) {
    int lane = threadIdx.x & 63;
    int row = blockIdx.x * 4 + __builtin_amdgcn_readfirstlane(threadIdx.x >> 6);
    float c0 = g[row * 3], c1 = g[row * 3 + 1], c2 = g[row * 3 + 2];
    const float* wr = W1 + lane * 6;
    Pg[(size_t)row * 64 + lane] = fmaf(wr[0], c0, fmaf(wr[1], c1, wr[2] * c2));
}

// ---------------------------------------------------------------- fused grid prep (stages B/C)
__global__ __launch_bounds__(256) void k_gridprep(
    const float* __restrict__ xsrc, const int* __restrict__ FPS,
    const float* __restrict__ W1, float* __restrict__ xgt, float* __restrict__ gT,
    float* __restrict__ gn, float* __restrict__ Pg) {
    int lane = threadIdx.x & 63, w = threadIdx.x >> 6;
    int row = blockIdx.x * 4 + w;
    int b = row >> 9, m = row & 511;
    int src = b * N_ + clampi(FPS[row], N_);
    float ge = xsrc[(size_t)src * 64 + lane];
    xgt[(size_t)row * 64 + lane] = ge;
    gT[((size_t)b * 64 + lane) * M_ + m] = ge;
    const float* wr = W1 + lane * 128;
    float s = 0.f, acc = 0.f;
#pragma unroll
    for (int c = 0; c < 64; c++) {
        float vc = __shfl(ge, c);
        s = fmaf(vc, vc, s);
        acc = fmaf(wr[c], vc, acc);
    }
    Pg[(size_t)row * 64 + lane] = acc;
    if (lane == 0) gn[row] = s;
}

// ---------------------------------------------------------------- fused prep + BN stats of y1
template <int D>
__global__ __launch_bounds__(256) void k_prep_stats(
    const float* __restrict__ q, const float* __restrict__ W1,
    const int* __restrict__ nearest, const float* __restrict__ T1,
    const float* __restrict__ T2, float* __restrict__ D0, float* __restrict__ S0,
    float* __restrict__ partial) {
    int lane = threadIdx.x & 63;
    int pt = blockIdx.x * 4 + __builtin_amdgcn_readfirstlane(threadIdx.x >> 6);
    int b = pt >> 12;
    float pa, pb;
    if constexpr (D == 3) {
        float c0 = q[pt * 3], c1 = q[pt * 3 + 1], c2 = q[pt * 3 + 2];
        const float* wr = W1 + lane * 6;
        pa = fmaf(wr[0], c0, fmaf(wr[1], c1, wr[2] * c2));
        pb = fmaf(wr[3], c0, fmaf(wr[4], c1, wr[5] * c2));
    } else {
        float ge = q[(size_t)pt * 64 + lane];
        const float* wr = W1 + lane * 128;
        pa = 0.f; pb = 0.f;
#pragma unroll
        for (int c = 0; c < 64; c++) {
            float sh = __shfl(ge, c);
            pa = fmaf(wr[c], sh, pa);
            pb = fmaf(wr[64 + c], sh, pb);
        }
    }
    float d0 = pb - pa, s0 = pb;
    size_t t = (size_t)pt * 64 + lane;
    D0[t] = d0;
    S0[t] = s0;
    size_t nr = ((size_t)b * M_ + clampi(nearest[pt], M_)) * 64 + lane;
    float t1 = T1[nr], t2 = T2[nr];
    float s1 = s0 + fmaf(49.f, d0, t1);
    float s2 = fmaf(s0, s0, fmaf(49.f * d0, d0, fmaf(2.f * d0, t1, t2)));
    STATS_STORE_64(s1, s2, partial)
}

// ---------------------------------------------------------------- stage-C output: bn+lrelu(max) exact
__global__ void k_apply0(const float* __restrict__ D0, const float* __restrict__ S0,
                         const int* __restrict__ nearest, const float* __restrict__ Mn,
                         const float* __restrict__ Mx, const float* __restrict__ prm,
                         float* __restrict__ xout) {
    int t = blockIdx.x * 256 + threadIdx.x;
    int pt = t >> 6, o = t & 63;
    int b = pt >> 12;
    size_t nr = ((size_t)b * M_ + clampi(nearest[pt], M_)) * 64 + o;
    float d0 = D0[t], s0 = S0[t];
    float a = prm[o], sh = prm[64 + o];
    float v = a > 0.f ? fmaxf(s0, d0 + Mx[nr]) : fminf(s0, d0 + Mn[nr]);
    xout[t] = lrelu(fmaf(a, v, sh));
}

// ---------------------------------------------------------------- pass1: bn1+lrelu -> conv2 -> stats+min/max
__global__ __launch_bounds__(256) void k_pass1(
    const float* __restrict__ Pg, const float* __restrict__ D0,
    const float* __restrict__ S0, const int* __restrict__ nearest,
    const int* __restrict__ nbr, const float* __restrict__ prm1,
    const float* __restrict__ W2, float* __restrict__ partial,
    float* __restrict__ mn_out, float* __restrict__ mx_out) {
    __shared__ float tile[4][64 * 17];
    __shared__ float ls1[256], ls2[256];
    int lane = threadIdx.x & 63;
    int wv = __builtin_amdgcn_readfirstlane(threadIdx.x >> 6);
    int pt = blockIdx.x * 4 + wv;
    int b = pt >> 12;
    int nr = clampi(nearest[pt], M_);
    const int* nrow = nbr + ((size_t)b * M_ + nr) * K_;
    int k = lane;
    int idx = (k >= 1 && k < K_) ? clampi(nrow[k], M_) : 0;
    const float4* src = (k == 0) ? (const float4*)(S0 + (size_t)pt * 64)
                                 : (const float4*)(Pg + ((size_t)b * M_ + idx) * 64);
    const float4* d0r = (const float4*)(D0 + (size_t)pt * 64);
    const float4* a4 = (const float4*)(prm1);
    const float4* s4 = (const float4*)(prm1 + 64);
    float dscale = (k == 0) ? 0.f : 1.f;
    float z[64];
#pragma unroll
    for (int c4 = 0; c4 < 16; c4++) {
        float4 v = src[c4]; float4 d = d0r[c4]; float4 a = a4[c4]; float4 s = s4[c4];
        z[4 * c4 + 0] = lrelu(fmaf(a.x, fmaf(dscale, d.x, v.x), s.x));
        z[4 * c4 + 1] = lrelu(fmaf(a.y, fmaf(dscale, d.y, v.y), s.y));
        z[4 * c4 + 2] = lrelu(fmaf(a.z, fmaf(dscale, d.z, v.z), s.z));
        z[4 * c4 + 3] = lrelu(fmaf(a.w, fmaf(dscale, d.w, v.w), s.w));
    }
    float* tl = tile[wv];
    int o_l = lane & 15, kg = lane >> 4;
#pragma clang loop unroll(disable)
    for (int ch = 0; ch < 4; ch++) {
#pragma clang loop unroll(disable)
        for (int og = 0; og < 4; og++) {
            int obase = ch * 16 + og * 4;
            const float4* wr0 = (const float4*)(W2 + (obase + 0) * 64);
            const float4* wr1 = (const float4*)(W2 + (obase + 1) * 64);
            const float4* wr2 = (const float4*)(W2 + (obase + 2) * 64);
            const float4* wr3 = (const float4*)(W2 + (obase + 3) * 64);
            float a0 = 0.f, a1 = 0.f, a2 = 0.f, a3 = 0.f;
#pragma unroll
            for (int c4 = 0; c4 < 16; c4++) {
                float z0 = z[4 * c4 + 0], z1 = z[4 * c4 + 1];
                float z2 = z[4 * c4 + 2], z3 = z[4 * c4 + 3];
                float4 w0 = wr0[c4], w1 = wr1[c4], w2 = wr2[c4], w3 = wr3[c4];
                a0 = fmaf(w0.x, z0, a0); a0 = fmaf(w0.y, z1, a0);
                a0 = fmaf(w0.z, z2, a0); a0 = fmaf(w0.w, z3, a0);
                a1 = fmaf(w1.x, z0, a1); a1 = fmaf(w1.y, z1, a1);
                a1 = fmaf(w1.z, z2, a1); a1 = fmaf(w1.w, z3, a1);
                a2 = fmaf(w2.x, z0, a2); a2 = fmaf(w2.y, z1, a2);
                a2 = fmaf(w2.z, z2, a2); a2 = fmaf(w2.w, z3, a2);
                a3 = fmaf(w3.x, z0, a3); a3 = fmaf(w3.y, z1, a3);
                a3 = fmaf(w3.z, z2, a3); a3 = fmaf(w3.w, z3, a3);
            }
            tl[lane * 17 + og * 4 + 0] = a0;
            tl[lane * 17 + og * 4 + 1] = a1;
            tl[lane * 17 + og * 4 + 2] = a2;
            tl[lane * 17 + og * 4 + 3] = a3;
        }
        float p1 = 0.f, p2 = 0.f, pm = -1e30f, pn = 1e30f;
#pragma unroll
        for (int i = 0; i < 16; i++) {
            int kk = kg * 16 + i;
            if (kk < K_) {
                float v = tl[kk * 17 + o_l];
                p1 += v; p2 = fmaf(v, v, p2);
                pm = fmaxf(pm, v); pn = fminf(pn, v);
            }
        }
        p1 += __shfl_xor(p1, 16); p1 += __shfl_xor(p1, 32);
        p2 += __shfl_xor(p2, 16); p2 += __shfl_xor(p2, 32);
        pm = fmaxf(pm, __shfl_xor(pm, 16)); pm = fmaxf(pm, __shfl_xor(pm, 32));
        pn = fminf(pn, __shfl_xor(pn, 16)); pn = fminf(pn, __shfl_xor(pn, 32));
        if (lane < 16) {
            int o = ch * 16 + lane;
            mn_out[(size_t)pt * 64 + o] = pn;
            mx_out[(size_t)pt * 64 + o] = pm;
            ls1[wv * 64 + o] = p1;
            ls2[wv * 64 + o] = p2;
        }
    }
    __syncthreads();
    if (threadIdx.x < 64) {
        int t = threadIdx.x;
        float a1 = ls1[t] + ls1[64 + t] + ls1[128 + t] + ls1[192 + t];
        float a2 = ls2[t] + ls2[64 + t] + ls2[128 + t] + ls2[192 + t];
        float* sp = partial + (size_t)blockIdx.x * 128;
        sp[t] = a1; sp[64 + t] = a2;
    }
}

// ---------------------------------------------------------------- apply bn+lrelu to min/max (exact)
__global__ void k_apply(const float* __restrict__ mn, const float* __restrict__ mx,
                        const float* __restrict__ prm, float* __restrict__ xout) {
    int t = blockIdx.x * 256 + threadIdx.x;
    int o = t & 63;
    float a = prm[o], sh = prm[64 + o];
    float v = a > 0.f ? mx[t] : mn[t];
    xout[t] = lrelu(fmaf(a, v, sh));
}

// ---------------------------------------------------------------- fused reduce+finalize (32 blocks)
// Level-1: block b sums its fixed slot range (unrolled, double, fixed order) -> redbuf.
// Then a 32-block fence (cheap) and the last block folds 32 slots in fixed order -> prm.
// Bit-identical arithmetic to the round-9 k_reduce + k_finalize pair.
template <int NP, int O>
__global__ __launch_bounds__(256) void k_redfin(
    const float* __restrict__ partial, double* __restrict__ red,
    int* __restrict__ counter, int C,
    const float* __restrict__ g, const float* __restrict__ bt,
    float* __restrict__ prm) {
    constexpr int VALS = 2 * O;
    constexpr int G = NP / 32;
    int b = blockIdx.x;   // 32 blocks
    for (int v = threadIdx.x; v < VALS; v += 256) {
        const float* p = partial + (size_t)b * G * VALS + v;
        double s = 0.0;
#pragma unroll
        for (int k = 0; k < G; k++) s += p[(size_t)k * VALS];
        red[(size_t)b * VALS + v] = s;
    }
    __threadfence();
    __syncthreads();
    __shared__ bool isLast;
    if (threadIdx.x == 0) isLast = (atomicAdd(counter, 1) == 31);
    __syncthreads();
    if (!isLast) return;
    __threadfence();
    for (int o = threadIdx.x; o < O; o += 256) {
        double s1 = 0.0, s2 = 0.0;
#pragma unroll
        for (int k = 0; k < 32; k++) {
            s1 += red[(size_t)k * VALS + o];
            s2 += red[(size_t)k * VALS + O + o];
        }
        double m = s1 / C, var = s2 / C - m * m;
        if (var < 0) var = 0;
        float sc = g[o] / sqrtf((float)var + EPS_);
        prm[o] = sc;
        prm[O + o] = bt[o] - (float)m * sc;
    }
}

// ---------------------------------------------------------------- W6 conv (192->512), x3 gathered via FPS
__global__ __launch_bounds__(256) void k_conv_w6(
    const float* __restrict__ x1gt, const float* __restrict__ x2gt,
    const float* __restrict__ x3t, const int* __restrict__ FPS,
    const float* __restrict__ W6, float* __restrict__ y6, float* __restrict__ partial) {
    __shared__ float vl[8][192];
    int b = blockIdx.x / (M_ / 8);
    int m0 = (blockIdx.x % (M_ / 8)) * 8;
    for (int i = threadIdx.x; i < 8 * 192; i += 256) {
        int mi = i / 192, c = i % 192;
        float v;
        if (c < 128) {
            const float* src = c < 64 ? x1gt : x2gt;
            v = src[((size_t)b * M_ + m0 + mi) * 64 + (c & 63)];
        } else {
            int src = b * N_ + clampi(FPS[b * M_ + m0 + mi], N_);
            v = x3t[(size_t)src * 64 + (c - 128)];
        }
        vl[mi][c] = v;
    }
    __syncthreads();
    float acc0[8] = {0}, acc1[8] = {0};
    int o0 = threadIdx.x, o1 = threadIdx.x + 256;
    for (int c = 0; c < 192; c++) {
        float w0 = W6[o0 * 192 + c];
        float w1 = W6[o1 * 192 + c];
#pragma unroll
        for (int m = 0; m < 8; m++) { float v = vl[m][c]; acc0[m] = fmaf(w0, v, acc0[m]); acc1[m] = fmaf(w1, v, acc1[m]); }
    }
    float s1a = 0, s2a = 0, s1b = 0, s2b = 0;
    for (int m = 0; m < 8; m++) {
        float ya = acc0[m], yb = acc1[m];
        y6[((size_t)b * M_ + m0 + m) * 512 + o0] = ya;
        y6[((size_t)b * M_ + m0 + m) * 512 + o1] = yb;
        s1a += ya; s2a = fmaf(ya, ya, s2a); s1b += yb; s2b = fmaf(yb, yb, s2b);
    }
    float* sp = partial + (size_t)blockIdx.x * 1024;
    sp[o0] = s1a; sp[512 + o0] = s2a;
    sp[o1] = s1b; sp[512 + o1] = s2b;
}

// ---------------------------------------------------------------- bn6+lrelu+max over M
__global__ void k_maxM(const float* __restrict__ y6, const float* __restrict__ prm,
                       float* __restrict__ xgmax) {
    int blk = blockIdx.x;
    int b = blk >> 4;
    int o = ((blk & 15) << 5) + (threadIdx.x & 31);
    int mg = threadIdx.x >> 5;
    float a = prm[o], sh = prm[512 + o];
    float mx = -1e30f;
    for (int m = mg; m < M_; m += 8)
        mx = fmaxf(mx, lrelu(fmaf(a, y6[((size_t)b * M_ + m) * 512 + o], sh)));
    __shared__ float red[256];
    red[threadIdx.x] = mx;
    __syncthreads();
    for (int s = 128; s >= 32; s >>= 1) {
        if (threadIdx.x < s) red[threadIdx.x] = fmaxf(red[threadIdx.x], red[threadIdx.x + s]);
        __syncthreads();
    }
    if (threadIdx.x < 32) xgmax[b * 512 + o] = red[threadIdx.x];
}

// ---------------------------------------------------------------- P7: wave per output (fixed xor tree)
__global__ __launch_bounds__(256) void k_p7(const float* __restrict__ xgmax,
                                            const float* __restrict__ W7,
                                            float* __restrict__ p7) {
    int lane = threadIdx.x & 63, w = threadIdx.x >> 6;
    int t = blockIdx.x * 4 + w;     // 0..255
    int b = t >> 7, o = t & 127;
    float acc = 0.f;
#pragma unroll
    for (int j = 0; j < 8; j++) {
        int c = j * 64 + lane;
        acc = fmaf(W7[o * 704 + c], xgmax[b * 512 + c], acc);
    }
    for (int off = 32; off; off >>= 1) acc += __shfl_xor(acc, off);
    if (lane == 0) p7[t] = acc;
}

// ---------------------------------------------------------------- W7 conv (704->128), 192 variable
__global__ __launch_bounds__(256) void k_conv_w7(
    const float* __restrict__ x1t, const float* __restrict__ x2t,
    const float* __restrict__ x3t, const float* __restrict__ p7,
    const float* __restrict__ W7, float* __restrict__ y7, float* __restrict__ partial) {
    __shared__ float vl[16][192];
    int item0 = blockIdx.x * 16;
    for (int i = threadIdx.x; i < 16 * 192; i += 256) {
        int it = i / 192, c = i % 192;
        const float* src = c < 64 ? x1t : (c < 128 ? x2t : x3t);
        vl[it][c] = src[((size_t)(item0 + it)) * 64 + (c & 63)];
    }
    __syncthreads();
    int o = threadIdx.x & 127, h = threadIdx.x >> 7;
    float acc[8] = {0};
    for (int c = 0; c < 192; c++) {
        float w = W7[o * 704 + 512 + c];
#pragma unroll
        for (int i = 0; i < 8; i++) acc[i] = fmaf(w, vl[h * 8 + i][c], acc[i]);
    }
    float s1 = 0, s2 = 0;
    for (int i = 0; i < 8; i++) {
        int item = item0 + h * 8 + i;
        int b = item / N_;
        float yv = p7[b * 128 + o] + acc[i];
        y7[(size_t)item * 128 + o] = yv;
        s1 += yv; s2 = fmaf(yv, yv, s2);
    }
    __shared__ float r1[256], r2[256];
    r1[threadIdx.x] = s1; r2[threadIdx.x] = s2;
    __syncthreads();
    if (threadIdx.x < 128) {
        float* sp = partial + (size_t)blockIdx.x * 256;
        sp[threadIdx.x] = r1[threadIdx.x] + r1[threadIdx.x + 128];
        sp[128 + threadIdx.x] = r2[threadIdx.x] + r2[threadIdx.x + 128];
    }
}

// ---------------------------------------------------------------- W8 conv (128->64)
__global__ __launch_bounds__(256) void k_conv_w8(
    const float* __restrict__ y7, const float* __restrict__ prm7,
    const float* __restrict__ W8, float* __restrict__ y8, float* __restrict__ partial) {
    int lane = threadIdx.x & 63;
    int item = blockIdx.x * 4 + (threadIdx.x >> 6);
    float W0[64], W1r[64];
#pragma unroll
    for (int c = 0; c < 64; c++) {
        W0[c] = W8[lane * 128 + c];
        W1r[c] = W8[lane * 128 + 64 + c];
    }
    float a0 = prm7[lane], sh0 = prm7[128 + lane];
    float a1 = prm7[64 + lane], sh1 = prm7[128 + 64 + lane];
    float z0 = lrelu(fmaf(a0, y7[(size_t)item * 128 + lane], sh0));
    float z1 = lrelu(fmaf(a1, y7[(size_t)item * 128 + 64 + lane], sh1));
    float acc = 0.f;
#pragma unroll
    for (int c = 0; c < 64; c++) {
        acc = fmaf(W0[c], __shfl(z0, c), acc);
        acc = fmaf(W1r[c], __shfl(z1, c), acc);
    }
    y8[(size_t)item * 64 + lane] = acc;
    STATS_STORE_64(acc, acc * acc, partial)
}

// ---------------------------------------------------------------- final: bn8+lrelu, W9 -> out
__global__ __launch_bounds__(256) void k_final(
    const float* __restrict__ y8, const float* __restrict__ prm8,
    const float* __restrict__ W9, void* __restrict__ out, const int* __restrict__ flag) {
    __shared__ float zl[2][64];
    int item0 = blockIdx.x * 2;
    if (threadIdx.x < 128) {
        int it = threadIdx.x >> 6, c = threadIdx.x & 63;
        float z = fmaf(prm8[c], y8[(size_t)(item0 + it) * 64 + c], prm8[64 + c]);
        zl[it][c] = lrelu(z);
    }
    __syncthreads();
    int it = threadIdx.x >> 7, o = threadIdx.x & 127;
    float acc = 0.f;
#pragma unroll
    for (int c = 0; c < 64; c++) acc = fmaf(W9[o * 64 + c], zl[it][c], acc);
    size_t oi = (size_t)(item0 + it) * 128 + o;
    if (*flag) ((bf16*)out)[oi] = __float2bfloat16(acc);
    else ((float*)out)[oi] = acc;
}

// ---------------------------------------------------------------- host
extern "C" void kernel_launch(void* const* d_in, const int* in_sizes, int n_in,
                              void* d_out, int out_size, void* d_ws, size_t ws_size,
                              hipStream_t stream) {
    (void)in_sizes; (void)n_in; (void)out_size; (void)ws_size;
    const void* x = d_in[0];
    const void* xgrid = d_in[1];
    const int* FPS = (const int*)d_in[2];

    char* ws = (char*)d_ws;
    size_t off = 0;
    auto alloc = [&](size_t bytes) -> char* {
        char* p = ws + off;
        off = (off + bytes + 255) & ~(size_t)255;
        return p;
    };
    int* flag       = (int*)alloc(256);
    int* counters   = (int*)alloc(256);                            // 8 fence counters (32-block scale)
    float* partials = (float*)alloc(2048 * 128 * sizeof(float));   // 1 MB, per-block stats slots
    double* redbuf  = (double*)alloc(32 * 1024 * sizeof(double));  // 256 KB, level-1 sums
    float* prm      = (float*)alloc(8 * 1024 * sizeof(float));
    static const int wsz[9] = {384, 4096, 8192, 4096, 8192, 98304, 90112, 8192, 8192};
    static const int dims[8] = {64, 64, 64, 64, 64, 512, 128, 64};
    float* cW[9];
    for (int i = 0; i < 9; i++) cW[i] = (float*)alloc((size_t)wsz[i] * 4);
    float* cG[8];
    float* cB[8];
    for (int j = 0; j < 8; j++) {
        cG[j] = (float*)alloc((size_t)dims[j] * 4);
        cB[j] = (float*)alloc((size_t)dims[j] * 4);
    }
    float* xt    = (float*)alloc((size_t)BN * 3 * 4);
    float* gt    = (float*)alloc((size_t)BM * 3 * 4);
    float* gT3   = (float*)alloc((size_t)B_ * 3 * M_ * 4);
    float* gn    = (float*)alloc((size_t)BM * 4);
    int* nearest = (int*)alloc((size_t)BN * 4);
    int* nbr     = (int*)alloc((size_t)BM * K_ * 4);
    float* Pg    = (float*)alloc((size_t)BM * 64 * 4);
    float* x1t   = (float*)alloc((size_t)BN * 64 * 4);
    float* x2t   = (float*)alloc((size_t)BN * 64 * 4);
    float* x3t   = (float*)alloc((size_t)BN * 64 * 4);
    float* x1gt  = (float*)alloc((size_t)BM * 64 * 4);
    float* x2gt  = (float*)alloc((size_t)BM * 64 * 4);
    float* gT64  = (float*)alloc((size_t)B_ * 64 * M_ * 4);
    float* y6    = (float*)alloc((size_t)BM * 512 * 4);    // 2 MB
    float* xgmax = (float*)alloc((size_t)B_ * 512 * 4);
    float* p7    = (float*)alloc((size_t)B_ * 128 * 4);
    float* y7    = (float*)alloc((size_t)BN * 128 * 4);    // 4 MB
    float* y8    = (float*)alloc((size_t)BN * 64 * 4);     // 2 MB
    // Aliases (lifetimes verified; same layout as passing rounds):
    float* D0b = y7;
    float* S0b = y7 + (size_t)BN * 64;
    float* mnb = y8;
    float* mxb = y6;
    float* T1b = y6;
    float* T2b = y6 + (size_t)BM * 64;
    float* Mnb = y6 + (size_t)2 * BM * 64;
    float* Mxb = y6 + (size_t)3 * BM * 64;

    hipMemsetAsync(counters, 0, 8 * sizeof(int), stream);
    k_detect<<<1, 256, 0, stream>>>((const unsigned short*)x, flag);

    CvtArgs ca;
    for (int i = 0; i < 9; i++) ca.d[i] = {d_in[3 + i], cW[i], wsz[i]};
    for (int j = 0; j < 8; j++) {
        ca.d[9 + 2 * j]     = {d_in[12 + 2 * j], cG[j], dims[j]};
        ca.d[9 + 2 * j + 1] = {d_in[13 + 2 * j], cB[j], dims[j]};
    }
    k_convert<<<dim3(384, 25), 256, 0, stream>>>(ca, flag);
    k_transpose<<<(BN + 255) / 256, 256, 0, stream>>>(x, xgrid, flag, xt, gt, gT3, gn);

    const int PG = BN / 4;         // wave-per-point grids (2048)
    const int EW = BN * 64 / 256;  // elementwise grids
    const int CK = BN * K_;

    // ---- stage A (D=3, W1,W2) ----
    k_pgrid3<<<BM / 4, 256, 0, stream>>>(gt, cW[0], Pg);
    k_nearest3<<<BN / 16, 256, 0, stream>>>(xt, gt, gn, nearest);
    k_nbr2<3><<<BM / 4, 256, 0, stream>>>(gt, gT3, gn, Pg, nbr, T1b, T2b, Mnb, Mxb);
    k_prep_stats<3><<<PG, 256, 0, stream>>>(xt, cW[0], nearest, T1b, T2b, D0b, S0b, partials);
    k_redfin<2048, 64><<<32, 256, 0, stream>>>(partials, redbuf, counters + 0, CK, cG[0], cB[0], prm + 0 * 1024);
    k_pass1<<<PG, 256, 0, stream>>>(Pg, D0b, S0b, nearest, nbr, prm + 0 * 1024, cW[1], partials, mnb, mxb);
    k_redfin<2048, 64><<<32, 256, 0, stream>>>(partials, redbuf, counters + 1, CK, cG[1], cB[1], prm + 1 * 1024);
    k_apply<<<EW, 256, 0, stream>>>(mnb, mxb, prm + 1 * 1024, x1t);

    // ---- stage B (D=64, W3,W4) ----
    k_gridprep<<<BM / 4, 256, 0, stream>>>(x1t, FPS, cW[2], x1gt, gT64, gn, Pg);
    k_nearest64<<<PG, 256, 0, stream>>>(x1t, gT64, gn, nearest);
    k_nbr2<64><<<BM / 4, 256, 0, stream>>>(x1gt, gT64, gn, Pg, nbr, T1b, T2b, Mnb, Mxb);
    k_prep_stats<64><<<PG, 256, 0, stream>>>(x1t, cW[2], nearest, T1b, T2b, D0b, S0b, partials);
    k_redfin<2048, 64><<<32, 256, 0, stream>>>(partials, redbuf, counters + 2, CK, cG[2], cB[2], prm + 2 * 1024);
    k_pass1<<<PG, 256, 0, stream>>>(Pg, D0b, S0b, nearest, nbr, prm + 2 * 1024, cW[3], partials, mnb, mxb);
    k_redfin<2048, 64><<<32, 256, 0, stream>>>(partials, redbuf, counters + 3, CK, cG[3], cB[3], prm + 3 * 1024);
    k_apply<<<EW, 256, 0, stream>>>(mnb, mxb, prm + 3 * 1024, x2t);

    // ---- stage C (D=64, W5 single conv) ----
    k_gridprep<<<BM / 4, 256, 0, stream>>>(x2t, FPS, cW[4], x2gt, gT64, gn, Pg);
    k_nearest64<<<PG, 256, 0, stream>>>(x2t, gT64, gn, nearest);
    k_nbr2<64><<<BM / 4, 256, 0, stream>>>(x2gt, gT64, gn, Pg, nbr, T1b, T2b, Mnb, Mxb);
    k_prep_stats<64><<<PG, 256, 0, stream>>>(x2t, cW[4], nearest, T1b, T2b, D0b, S0b, partials);
    k_redfin<2048, 64><<<32, 256, 0, stream>>>(partials, redbuf, counters + 4, CK, cG[4], cB[4], prm + 4 * 1024);
    k_apply0<<<EW, 256, 0, stream>>>(D0b, S0b, nearest, Mnb, Mxb, prm + 4 * 1024, x3t);

    // ---- global MLP tail (x3 gather fused into k_conv_w6) ----
    k_conv_w6<<<BM / 8, 256, 0, stream>>>(x1gt, x2gt, x3t, FPS, cW[5], y6, partials);
    k_redfin<128, 512><<<32, 256, 0, stream>>>(partials, redbuf, counters + 5, BM, cG[5], cB[5], prm + 5 * 1024);
    k_maxM<<<B_ * 16, 256, 0, stream>>>(y6, prm + 5 * 1024, xgmax);
    k_p7<<<64, 256, 0, stream>>>(xgmax, cW[6], p7);
    k_conv_w7<<<BN / 16, 256, 0, stream>>>(x1t, x2t, x3t, p7, cW[6], y7, partials);
    k_redfin<512, 128><<<32, 256, 0, stream>>>(partials, redbuf, counters + 6, BN, cG[6], cB[6], prm + 6 * 1024);
    k_conv_w8<<<BN / 4, 256, 0, stream>>>(y7, prm + 6 * 1024, cW[7], y8, partials);
    k_redfin<2048, 64><<<32, 256, 0, stream>>>(partials, redbuf, counters + 7, BN, cG[7], cB[7], prm + 7 * 1024);
    k_final<<<BN / 2, 256, 0, stream>>>(y8, prm + 7 * 1024, cW[8], d_out, flag);
}

// Round 12
// 788.112 us; speedup vs baseline: 2.3353x; 1.1269x over previous
//
#include <hip/hip_runtime.h>
#include <hip/hip_bf16.h>

#define DEV __device__ __forceinline__
using bf16 = __hip_bfloat16;

static constexpr int B_ = 2, N_ = 4096, M_ = 512, K_ = 50;
static constexpr int BN = B_ * N_;   // 8192 points
static constexpr int BM = B_ * M_;   // 1024 grid points
static constexpr float EPS_ = 1e-5f;

DEV float lrelu(float z) { return z < 0.f ? 0.2f * z : z; }
DEV int clampi(int v, int hi) { return ((unsigned)v < (unsigned)hi) ? v : 0; }

// ---------------------------------------------------------------- dtype detect
__global__ void k_detect(const unsigned short* __restrict__ xw, int* __restrict__ flag) {
    int t = threadIdx.x;
    int cnt = 0;
    for (int i = t; i < 4096; i += 256) {
        int e = (xw[i] >> 7) & 0xFF;
        if (e >= 100 && e <= 140) cnt++;
    }
    __shared__ int sh[256];
    sh[t] = cnt;
    __syncthreads();
    for (int s = 128; s; s >>= 1) { if (t < s) sh[t] += sh[t + s]; __syncthreads(); }
    if (t == 0) *flag = (sh[0] >= 3300) ? 1 : 0;
}

// ---------------------------------------------------------------- convert params to f32
struct CvtDesc { const void* src; float* dst; int n; };
struct CvtArgs { CvtDesc d[25]; };
__global__ void k_convert(CvtArgs a, const int* __restrict__ flag) {
    CvtDesc dd = a.d[blockIdx.y];
    int i = blockIdx.x * 256 + threadIdx.x;
    if (i >= dd.n) return;
    float v = (*flag) ? __bfloat162float(((const bf16*)dd.src)[i])
                      : ((const float*)dd.src)[i];
    dd.dst[i] = v;
}

// ---------------------------------------------------------------- transposed weight copies (coalesced loads later)
struct CvtT { const void* src; float* dst; int O; int C; int stride; int off; };
struct CvtTArgs { CvtT d[4]; };
__global__ void k_convT(CvtTArgs a, const int* __restrict__ flag) {
    CvtT dd = a.d[blockIdx.y];
    int idx = blockIdx.x * 256 + threadIdx.x;
    if (idx >= dd.O * dd.C) return;
    int c = idx / dd.O, o = idx % dd.O;
    int si = o * dd.stride + dd.off + c;
    float v = (*flag) ? __bfloat162float(((const bf16*)dd.src)[si])
                      : ((const float*)dd.src)[si];
    dd.dst[idx] = v;   // dst[c*O + o]
}

// ---------------------------------------------------------------- transpose (flat regrid; + gn for grid)
DEV float rdval(const void* p, int i, int isbf) {
    return isbf ? __bfloat162float(((const bf16*)p)[i]) : ((const float*)p)[i];
}
__global__ void k_transpose(const void* __restrict__ x, const void* __restrict__ xg,
                            const int* __restrict__ flag,
                            float* __restrict__ xt, float* __restrict__ gt,
                            float* __restrict__ gT3, float* __restrict__ gn) {
    int isbf = *flag;
    int idx = blockIdx.x * 256 + threadIdx.x;
    if (idx < BN * 3) {
        int c = idx / BN, i = idx % BN;
        int b = i / N_, n = i % N_;
        xt[i * 3 + c] = rdval(x, (b * 3 + c) * N_ + n, isbf);
    } else {
        int r = idx - BN * 3;
        if (r < BM) {
            int b = r / M_, m = r % M_;
            float s = 0.f;
            for (int c = 0; c < 3; c++) {
                float v = rdval(xg, (b * 3 + c) * M_ + m, isbf);
                gt[r * 3 + c] = v;
                gT3[(b * 3 + c) * M_ + m] = v;
                s = fmaf(v, v, s);
            }
            gn[r] = s;
        }
    }
}

// ---------------------------------------------------------------- nearest D=3 body
DEV void nearest3_body(int blk, const float* __restrict__ q, const float* __restrict__ gt,
                       const float* __restrict__ gn, int* __restrict__ nearest) {
    int sub = threadIdx.x & 15;
    int pt = blk * 16 + (threadIdx.x >> 4);
    int b = pt >> 12;
    float q0 = q[pt * 3], q1 = q[pt * 3 + 1], q2 = q[pt * 3 + 2];
    float qn = q0 * q0 + q1 * q1 + q2 * q2;
    const float* gb = gt + (size_t)b * M_ * 3;
    const float* gnb = gn + b * M_;
    float best = 1e30f; int bi = 0x7fffffff;
    for (int j = 0; j < 32; j++) {
        int m = sub + 16 * j;
        float dot = q0 * gb[m * 3] + q1 * gb[m * 3 + 1] + q2 * gb[m * 3 + 2];
        float dv = qn + gnb[m] - 2.f * dot;
        if (dv < best || (dv == best && m < bi)) { best = dv; bi = m; }
    }
    for (int off = 8; off; off >>= 1) {
        float ov = __shfl_xor(best, off);
        int oi = __shfl_xor(bi, off);
        if (ov < best || (ov == best && oi < bi)) { best = ov; bi = oi; }
    }
    if (sub == 0) nearest[pt] = clampi(bi, M_);
}

// ---------------------------------------------------------------- nearest D=64 body (wave/point, m-vectorized)
DEV void nearest64_body(int blk, const float* __restrict__ q, const float* __restrict__ gT,
                        const float* __restrict__ gn, int* __restrict__ nearest) {
    int lane = threadIdx.x & 63;
    int pt = blk * 4 + __builtin_amdgcn_readfirstlane(threadIdx.x >> 6);
    int b = pt >> 12;
    const float* qrow = q + (size_t)pt * 64;
    float qs[64];
#pragma unroll
    for (int c = 0; c < 64; c++) qs[c] = qrow[c];
    float qn = 0.f;
#pragma unroll
    for (int c = 0; c < 64; c++) qn = fmaf(qs[c], qs[c], qn);
    const float* gTb = gT + (size_t)b * 64 * M_;
    float d[8] = {0.f, 0.f, 0.f, 0.f, 0.f, 0.f, 0.f, 0.f};
#pragma unroll
    for (int c = 0; c < 64; c++) {
        float qc = qs[c];
        float4 g0 = *(const float4*)(gTb + c * M_ + 4 * lane);
        float4 g1 = *(const float4*)(gTb + c * M_ + 256 + 4 * lane);
        d[0] = fmaf(qc, g0.x, d[0]); d[1] = fmaf(qc, g0.y, d[1]);
        d[2] = fmaf(qc, g0.z, d[2]); d[3] = fmaf(qc, g0.w, d[3]);
        d[4] = fmaf(qc, g1.x, d[4]); d[5] = fmaf(qc, g1.y, d[5]);
        d[6] = fmaf(qc, g1.z, d[6]); d[7] = fmaf(qc, g1.w, d[7]);
    }
    const float* gnb = gn + b * M_;
    float4 n0 = *(const float4*)(gnb + 4 * lane);
    float4 n1 = *(const float4*)(gnb + 256 + 4 * lane);
    float nn[8] = {n0.x, n0.y, n0.z, n0.w, n1.x, n1.y, n1.z, n1.w};
    float best = 1e30f; int bi = 0;
#pragma unroll
    for (int i = 0; i < 8; i++) {
        int m = (i < 4) ? (4 * lane + i) : (256 + 4 * lane + i - 4);
        float dv = qn + nn[i] - 2.f * d[i];
        if (dv < best || (dv == best && m < bi)) { best = dv; bi = m; }
    }
    for (int off = 32; off; off >>= 1) {
        float ov = __shfl_xor(best, off);
        int oi = __shfl_xor(bi, off);
        if (ov < best || (ov == best && oi < bi)) { best = ov; bi = oi; }
    }
    if (lane == 0) nearest[pt] = clampi(bi, M_);
}

// ---------------------------------------------------------------- grid KNN body + fused neighborhood stats
template <int D>
DEV void nbr2_body(int blk, const float* __restrict__ g, const float* __restrict__ gT,
                   const float* __restrict__ gn, const float* __restrict__ Pg,
                   int* __restrict__ nbr, float* __restrict__ T1, float* __restrict__ T2,
                   float* __restrict__ Mn, float* __restrict__ Mx) {
    int lane = threadIdx.x & 63, w = threadIdx.x >> 6;
    int row = blk * 4 + w;
    int b = row >> 9;
    const float* grow = g + (size_t)row * D;
    float qs[D];
#pragma unroll
    for (int c = 0; c < D; c++) qs[c] = grow[c];
    float qn = gn[row];
    const float* gTb = gT + (size_t)b * D * M_;
    const float* gnb = gn + b * M_;
    float d[8] = {0.f, 0.f, 0.f, 0.f, 0.f, 0.f, 0.f, 0.f};
#pragma unroll
    for (int c = 0; c < D; c++) {
        float qc = qs[c];
        float4 g0 = *(const float4*)(gTb + c * M_ + 4 * lane);
        float4 g1 = *(const float4*)(gTb + c * M_ + 256 + 4 * lane);
        d[0] = fmaf(qc, g0.x, d[0]); d[1] = fmaf(qc, g0.y, d[1]);
        d[2] = fmaf(qc, g0.z, d[2]); d[3] = fmaf(qc, g0.w, d[3]);
        d[4] = fmaf(qc, g1.x, d[4]); d[5] = fmaf(qc, g1.y, d[5]);
        d[6] = fmaf(qc, g1.z, d[6]); d[7] = fmaf(qc, g1.w, d[7]);
    }
    float4 n0 = *(const float4*)(gnb + 4 * lane);
    float4 n1 = *(const float4*)(gnb + 256 + 4 * lane);
    float dd[8];
    dd[0] = qn + n0.x - 2.f * d[0]; dd[1] = qn + n0.y - 2.f * d[1];
    dd[2] = qn + n0.z - 2.f * d[2]; dd[3] = qn + n0.w - 2.f * d[3];
    dd[4] = qn + n1.x - 2.f * d[4]; dd[5] = qn + n1.y - 2.f * d[5];
    dd[6] = qn + n1.z - 2.f * d[6]; dd[7] = qn + n1.w - 2.f * d[7];
    int mreg[8];
#pragma unroll
    for (int i = 0; i < 8; i++) mreg[i] = (i < 4) ? (4 * lane + i) : (256 + 4 * lane + i - 4);
    int myIdx = 0;
    for (int it = 0; it < K_; it++) {
        float bv = 1e30f; int bi = 0x7fffffff;
#pragma unroll
        for (int i = 0; i < 8; i++) {
            if (dd[i] < bv || (dd[i] == bv && mreg[i] < bi)) { bv = dd[i]; bi = mreg[i]; }
        }
        for (int off = 32; off; off >>= 1) {
            float ov = __shfl_xor(bv, off);
            int oi = __shfl_xor(bi, off);
            if (ov < bv || (ov == bv && oi < bi)) { bv = ov; bi = oi; }
        }
        bi = clampi(bi, M_);
        if (lane == it) { myIdx = bi; nbr[(size_t)row * K_ + it] = bi; }
#pragma unroll
        for (int i = 0; i < 8; i++) if (mreg[i] == bi) dd[i] = 1e30f;
    }
    const float* Pgb = Pg + (size_t)b * M_ * 64;
    float t1 = 0.f, t2 = 0.f, mn = 1e30f, mx = -1e30f;
#pragma unroll 7
    for (int k = 1; k < K_; k++) {
        int idx = __shfl(myIdx, k);
        float v = Pgb[(size_t)idx * 64 + lane];
        t1 += v; t2 = fmaf(v, v, t2);
        mn = fminf(mn, v); mx = fmaxf(mx, v);
    }
    size_t o = (size_t)row * 64 + lane;
    T1[o] = t1; T2[o] = t2; Mn[o] = mn; Mx[o] = mx;
}

// ---------------------------------------------------------------- fused KNN launches (independent bodies)
__global__ __launch_bounds__(256) void k_knn3(
    const float* __restrict__ q, const float* __restrict__ gt, const float* __restrict__ gT3,
    const float* __restrict__ gn, const float* __restrict__ Pg,
    int* __restrict__ nearest, int* __restrict__ nbr, float* __restrict__ T1,
    float* __restrict__ T2, float* __restrict__ Mn, float* __restrict__ Mx) {
    if (blockIdx.x < BN / 16) nearest3_body(blockIdx.x, q, gt, gn, nearest);
    else nbr2_body<3>(blockIdx.x - BN / 16, gt, gT3, gn, Pg, nbr, T1, T2, Mn, Mx);
}
__global__ __launch_bounds__(256) void k_knn64(
    const float* __restrict__ q, const float* __restrict__ xgt, const float* __restrict__ gT,
    const float* __restrict__ gn, const float* __restrict__ Pg,
    int* __restrict__ nearest, int* __restrict__ nbr, float* __restrict__ T1,
    float* __restrict__ T2, float* __restrict__ Mn, float* __restrict__ Mx) {
    if (blockIdx.x < BN / 4) nearest64_body(blockIdx.x, q, gT, gn, nearest);
    else nbr2_body<64>(blockIdx.x - BN / 4, xgt, gT, gn, Pg, nbr, T1, T2, Mn, Mx);
}

// ---------------------------------------------------------------- deterministic block stats store
#define STATS_STORE_64(s1v, s2v, partial)                                         \
    {                                                                             \
        __shared__ float r1_[256], r2_[256];                                      \
        r1_[threadIdx.x] = (s1v); r2_[threadIdx.x] = (s2v);                       \
        __syncthreads();                                                          \
        if (threadIdx.x < 64) {                                                   \
            int t_ = threadIdx.x;                                                 \
            float a1_ = r1_[t_] + r1_[t_ + 64] + r1_[t_ + 128] + r1_[t_ + 192];   \
            float a2_ = r2_[t_] + r2_[t_ + 64] + r2_[t_ + 128] + r2_[t_ + 192];   \
            float* sp_ = (partial) + (size_t)blockIdx.x * 128;                    \
            sp_[t_] = a1_; sp_[64 + t_] = a2_;                                    \
        }                                                                         \
    }

// ---------------------------------------------------------------- Pg for stage A (D=3)
__global__ __launch_bounds__(256) void k_pgrid3(const float* __restrict__ g,
                                                const float* __restrict__ W1,
                                                float* __restrict__ Pg) {
    int lane = threadIdx.x & 63;
    int row = blockIdx.x * 4 + __builtin_amdgcn_readfirstlane(threadIdx.x >> 6);
    float c0 = g[row * 3], c1 = g[row * 3 + 1], c2 = g[row * 3 + 2];
    const float* wr = W1 + lane * 6;
    Pg[(size_t)row * 64 + lane] = fmaf(wr[0], c0, fmaf(wr[1], c1, wr[2] * c2));
}

// ---------------------------------------------------------------- fused grid prep (stages B/C)
__global__ __launch_bounds__(256) void k_gridprep(
    const float* __restrict__ xsrc, const int* __restrict__ FPS,
    const float* __restrict__ W1, float* __restrict__ xgt, float* __restrict__ gT,
    float* __restrict__ gn, float* __restrict__ Pg) {
    int lane = threadIdx.x & 63, w = threadIdx.x >> 6;
    int row = blockIdx.x * 4 + w;
    int b = row >> 9, m = row & 511;
    int src = b * N_ + clampi(FPS[row], N_);
    float ge = xsrc[(size_t)src * 64 + lane];
    xgt[(size_t)row * 64 + lane] = ge;
    gT[((size_t)b * 64 + lane) * M_ + m] = ge;
    const float* wr = W1 + lane * 128;
    float s = 0.f, acc = 0.f;
#pragma unroll
    for (int c = 0; c < 64; c++) {
        float vc = __shfl(ge, c);
        s = fmaf(vc, vc, s);
        acc = fmaf(wr[c], vc, acc);
    }
    Pg[(size_t)row * 64 + lane] = acc;
    if (lane == 0) gn[row] = s;
}

// ---------------------------------------------------------------- fused prep + BN stats of y1
template <int D>
__global__ __launch_bounds__(256) void k_prep_stats(
    const float* __restrict__ q, const float* __restrict__ W1,
    const int* __restrict__ nearest, const float* __restrict__ T1,
    const float* __restrict__ T2, float* __restrict__ D0, float* __restrict__ S0,
    float* __restrict__ partial) {
    int lane = threadIdx.x & 63;
    int pt = blockIdx.x * 4 + __builtin_amdgcn_readfirstlane(threadIdx.x >> 6);
    int b = pt >> 12;
    float pa, pb;
    if constexpr (D == 3) {
        float c0 = q[pt * 3], c1 = q[pt * 3 + 1], c2 = q[pt * 3 + 2];
        const float* wr = W1 + lane * 6;
        pa = fmaf(wr[0], c0, fmaf(wr[1], c1, wr[2] * c2));
        pb = fmaf(wr[3], c0, fmaf(wr[4], c1, wr[5] * c2));
    } else {
        float ge = q[(size_t)pt * 64 + lane];
        const float* wr = W1 + lane * 128;
        pa = 0.f; pb = 0.f;
#pragma unroll
        for (int c = 0; c < 64; c++) {
            float sh = __shfl(ge, c);
            pa = fmaf(wr[c], sh, pa);
            pb = fmaf(wr[64 + c], sh, pb);
        }
    }
    float d0 = pb - pa, s0 = pb;
    size_t t = (size_t)pt * 64 + lane;
    D0[t] = d0;
    S0[t] = s0;
    size_t nr = ((size_t)b * M_ + clampi(nearest[pt], M_)) * 64 + lane;
    float t1 = T1[nr], t2 = T2[nr];
    float s1 = s0 + fmaf(49.f, d0, t1);
    float s2 = fmaf(s0, s0, fmaf(49.f * d0, d0, fmaf(2.f * d0, t1, t2)));
    STATS_STORE_64(s1, s2, partial)
}

// ---------------------------------------------------------------- stage-C output: bn+lrelu(max) exact
__global__ void k_apply0(const float* __restrict__ D0, const float* __restrict__ S0,
                         const int* __restrict__ nearest, const float* __restrict__ Mn,
                         const float* __restrict__ Mx, const float* __restrict__ prm,
                         float* __restrict__ xout) {
    int t = blockIdx.x * 256 + threadIdx.x;
    int pt = t >> 6, o = t & 63;
    int b = pt >> 12;
    size_t nr = ((size_t)b * M_ + clampi(nearest[pt], M_)) * 64 + o;
    float d0 = D0[t], s0 = S0[t];
    float a = prm[o], sh = prm[64 + o];
    float v = a > 0.f ? fmaxf(s0, d0 + Mx[nr]) : fminf(s0, d0 + Mn[nr]);
    xout[t] = lrelu(fmaf(a, v, sh));
}

// ---------------------------------------------------------------- pass1: bn1+lrelu -> conv2 -> stats+min/max
__global__ __launch_bounds__(256) void k_pass1(
    const float* __restrict__ Pg, const float* __restrict__ D0,
    const float* __restrict__ S0, const int* __restrict__ nearest,
    const int* __restrict__ nbr, const float* __restrict__ prm1,
    const float* __restrict__ W2, float* __restrict__ partial,
    float* __restrict__ mn_out, float* __restrict__ mx_out) {
    __shared__ float tile[4][64 * 17];
    __shared__ float ls1[256], ls2[256];
    int lane = threadIdx.x & 63;
    int wv = __builtin_amdgcn_readfirstlane(threadIdx.x >> 6);
    int pt = blockIdx.x * 4 + wv;
    int b = pt >> 12;
    int nr = clampi(nearest[pt], M_);
    const int* nrow = nbr + ((size_t)b * M_ + nr) * K_;
    int k = lane;
    int idx = (k >= 1 && k < K_) ? clampi(nrow[k], M_) : 0;
    const float4* src = (k == 0) ? (const float4*)(S0 + (size_t)pt * 64)
                                 : (const float4*)(Pg + ((size_t)b * M_ + idx) * 64);
    const float4* d0r = (const float4*)(D0 + (size_t)pt * 64);
    const float4* a4 = (const float4*)(prm1);
    const float4* s4 = (const float4*)(prm1 + 64);
    float dscale = (k == 0) ? 0.f : 1.f;
    float z[64];
#pragma unroll
    for (int c4 = 0; c4 < 16; c4++) {
        float4 v = src[c4]; float4 d = d0r[c4]; float4 a = a4[c4]; float4 s = s4[c4];
        z[4 * c4 + 0] = lrelu(fmaf(a.x, fmaf(dscale, d.x, v.x), s.x));
        z[4 * c4 + 1] = lrelu(fmaf(a.y, fmaf(dscale, d.y, v.y), s.y));
        z[4 * c4 + 2] = lrelu(fmaf(a.z, fmaf(dscale, d.z, v.z), s.z));
        z[4 * c4 + 3] = lrelu(fmaf(a.w, fmaf(dscale, d.w, v.w), s.w));
    }
    float* tl = tile[wv];
    int o_l = lane & 15, kg = lane >> 4;
#pragma clang loop unroll(disable)
    for (int ch = 0; ch < 4; ch++) {
#pragma clang loop unroll(disable)
        for (int og = 0; og < 4; og++) {
            int obase = ch * 16 + og * 4;
            const float4* wr0 = (const float4*)(W2 + (obase + 0) * 64);
            const float4* wr1 = (const float4*)(W2 + (obase + 1) * 64);
            const float4* wr2 = (const float4*)(W2 + (obase + 2) * 64);
            const float4* wr3 = (const float4*)(W2 + (obase + 3) * 64);
            float a0 = 0.f, a1 = 0.f, a2 = 0.f, a3 = 0.f;
#pragma unroll
            for (int c4 = 0; c4 < 16; c4++) {
                float z0 = z[4 * c4 + 0], z1 = z[4 * c4 + 1];
                float z2 = z[4 * c4 + 2], z3 = z[4 * c4 + 3];
                float4 w0 = wr0[c4], w1 = wr1[c4], w2 = wr2[c4], w3 = wr3[c4];
                a0 = fmaf(w0.x, z0, a0); a0 = fmaf(w0.y, z1, a0);
                a0 = fmaf(w0.z, z2, a0); a0 = fmaf(w0.w, z3, a0);
                a1 = fmaf(w1.x, z0, a1); a1 = fmaf(w1.y, z1, a1);
                a1 = fmaf(w1.z, z2, a1); a1 = fmaf(w1.w, z3, a1);
                a2 = fmaf(w2.x, z0, a2); a2 = fmaf(w2.y, z1, a2);
                a2 = fmaf(w2.z, z2, a2); a2 = fmaf(w2.w, z3, a2);
                a3 = fmaf(w3.x, z0, a3); a3 = fmaf(w3.y, z1, a3);
                a3 = fmaf(w3.z, z2, a3); a3 = fmaf(w3.w, z3, a3);
            }
            tl[lane * 17 + og * 4 + 0] = a0;
            tl[lane * 17 + og * 4 + 1] = a1;
            tl[lane * 17 + og * 4 + 2] = a2;
            tl[lane * 17 + og * 4 + 3] = a3;
        }
        float p1 = 0.f, p2 = 0.f, pm = -1e30f, pn = 1e30f;
#pragma unroll
        for (int i = 0; i < 16; i++) {
            int kk = kg * 16 + i;
            if (kk < K_) {
                float v = tl[kk * 17 + o_l];
                p1 += v; p2 = fmaf(v, v, p2);
                pm = fmaxf(pm, v); pn = fminf(pn, v);
            }
        }
        p1 += __shfl_xor(p1, 16); p1 += __shfl_xor(p1, 32);
        p2 += __shfl_xor(p2, 16); p2 += __shfl_xor(p2, 32);
        pm = fmaxf(pm, __shfl_xor(pm, 16)); pm = fmaxf(pm, __shfl_xor(pm, 32));
        pn = fminf(pn, __shfl_xor(pn, 16)); pn = fminf(pn, __shfl_xor(pn, 32));
        if (lane < 16) {
            int o = ch * 16 + lane;
            mn_out[(size_t)pt * 64 + o] = pn;
            mx_out[(size_t)pt * 64 + o] = pm;
            ls1[wv * 64 + o] = p1;
            ls2[wv * 64 + o] = p2;
        }
    }
    __syncthreads();
    if (threadIdx.x < 64) {
        int t = threadIdx.x;
        float a1 = ls1[t] + ls1[64 + t] + ls1[128 + t] + ls1[192 + t];
        float a2 = ls2[t] + ls2[64 + t] + ls2[128 + t] + ls2[192 + t];
        float* sp = partial + (size_t)blockIdx.x * 128;
        sp[t] = a1; sp[64 + t] = a2;
    }
}

// ---------------------------------------------------------------- apply bn+lrelu to min/max (exact)
__global__ void k_apply(const float* __restrict__ mn, const float* __restrict__ mx,
                        const float* __restrict__ prm, float* __restrict__ xout) {
    int t = blockIdx.x * 256 + threadIdx.x;
    int o = t & 63;
    float a = prm[o], sh = prm[64 + o];
    float v = a > 0.f ? mx[t] : mn[t];
    xout[t] = lrelu(fmaf(a, v, sh));
}

// ---------------------------------------------------------------- fused reduce+finalize (32 blocks)
template <int NP, int O>
__global__ __launch_bounds__(256) void k_redfin(
    const float* __restrict__ partial, double* __restrict__ red,
    int* __restrict__ counter, int C,
    const float* __restrict__ g, const float* __restrict__ bt,
    float* __restrict__ prm) {
    constexpr int VALS = 2 * O;
    constexpr int G = NP / 32;
    int b = blockIdx.x;   // 32 blocks
    for (int v = threadIdx.x; v < VALS; v += 256) {
        const float* p = partial + (size_t)b * G * VALS + v;
        double s = 0.0;
#pragma unroll
        for (int k = 0; k < G; k++) s += p[(size_t)k * VALS];
        red[(size_t)b * VALS + v] = s;
    }
    __threadfence();
    __syncthreads();
    __shared__ bool isLast;
    if (threadIdx.x == 0) isLast = (atomicAdd(counter, 1) == 31);
    __syncthreads();
    if (!isLast) return;
    __threadfence();
    for (int o = threadIdx.x; o < O; o += 256) {
        double s1 = 0.0, s2 = 0.0;
#pragma unroll
        for (int k = 0; k < 32; k++) {
            s1 += red[(size_t)k * VALS + o];
            s2 += red[(size_t)k * VALS + O + o];
        }
        double m = s1 / C, var = s2 / C - m * m;
        if (var < 0) var = 0;
        float sc = g[o] / sqrtf((float)var + EPS_);
        prm[o] = sc;
        prm[O + o] = bt[o] - (float)m * sc;
    }
}

// ---------------------------------------------------------------- W6 conv (192->512), Wt-coalesced, 4-row tiles
__global__ __launch_bounds__(256) void k_conv_w6(
    const float* __restrict__ x1gt, const float* __restrict__ x2gt,
    const float* __restrict__ x3t, const int* __restrict__ FPS,
    const float* __restrict__ W6t, float* __restrict__ y6, float* __restrict__ partial) {
    __shared__ float vl[4][192];
    int b = blockIdx.x / 128;
    int m0 = (blockIdx.x % 128) * 4;
    for (int i = threadIdx.x; i < 4 * 192; i += 256) {
        int mi = i / 192, c = i % 192;
        float v;
        if (c < 128) {
            const float* src = c < 64 ? x1gt : x2gt;
            v = src[((size_t)b * M_ + m0 + mi) * 64 + (c & 63)];
        } else {
            int s = b * N_ + clampi(FPS[b * M_ + m0 + mi], N_);
            v = x3t[(size_t)s * 64 + (c - 128)];
        }
        vl[mi][c] = v;
    }
    __syncthreads();
    float acc0[4] = {0}, acc1[4] = {0};
    int o0 = threadIdx.x, o1 = threadIdx.x + 256;
    for (int c = 0; c < 192; c++) {
        float w0 = W6t[c * 512 + o0];
        float w1 = W6t[c * 512 + o1];
#pragma unroll
        for (int m = 0; m < 4; m++) { float v = vl[m][c]; acc0[m] = fmaf(w0, v, acc0[m]); acc1[m] = fmaf(w1, v, acc1[m]); }
    }
    float s1a = 0, s2a = 0, s1b = 0, s2b = 0;
    for (int m = 0; m < 4; m++) {
        float ya = acc0[m], yb = acc1[m];
        y6[((size_t)b * M_ + m0 + m) * 512 + o0] = ya;
        y6[((size_t)b * M_ + m0 + m) * 512 + o1] = yb;
        s1a += ya; s2a = fmaf(ya, ya, s2a); s1b += yb; s2b = fmaf(yb, yb, s2b);
    }
    float* sp = partial + (size_t)blockIdx.x * 1024;
    sp[o0] = s1a; sp[512 + o0] = s2a;
    sp[o1] = s1b; sp[512 + o1] = s2b;
}

// ---------------------------------------------------------------- bn6+lrelu+max over M (128 blocks)
__global__ void k_maxM(const float* __restrict__ y6, const float* __restrict__ prm,
                       float* __restrict__ xgmax) {
    int blk = blockIdx.x;            // B_*64
    int b = blk >> 6;
    int obase = (blk & 63) << 3;
    int o = obase + (threadIdx.x & 7);
    int mg = threadIdx.x >> 3;       // 32 m-groups
    float a = prm[o], sh = prm[512 + o];
    float mx = -1e30f;
    for (int m = mg; m < M_; m += 32)
        mx = fmaxf(mx, lrelu(fmaf(a, y6[((size_t)b * M_ + m) * 512 + o], sh)));
    __shared__ float red[256];
    red[threadIdx.x] = mx;
    __syncthreads();
    for (int s = 128; s >= 8; s >>= 1) {
        if (threadIdx.x < s) red[threadIdx.x] = fmaxf(red[threadIdx.x], red[threadIdx.x + s]);
        __syncthreads();
    }
    if (threadIdx.x < 8) xgmax[b * 512 + obase + threadIdx.x] = red[threadIdx.x];
}

// ---------------------------------------------------------------- P7: wave per output (fixed xor tree)
__global__ __launch_bounds__(256) void k_p7(const float* __restrict__ xgmax,
                                            const float* __restrict__ W7,
                                            float* __restrict__ p7) {
    int lane = threadIdx.x & 63, w = threadIdx.x >> 6;
    int t = blockIdx.x * 4 + w;     // 0..255
    int b = t >> 7, o = t & 127;
    float acc = 0.f;
#pragma unroll
    for (int j = 0; j < 8; j++) {
        int c = j * 64 + lane;
        acc = fmaf(W7[o * 704 + c], xgmax[b * 512 + c], acc);
    }
    for (int off = 32; off; off >>= 1) acc += __shfl_xor(acc, off);
    if (lane == 0) p7[t] = acc;
}

// ---------------------------------------------------------------- W7 conv (704->128), Wt-coalesced
__global__ __launch_bounds__(256) void k_conv_w7(
    const float* __restrict__ x1t, const float* __restrict__ x2t,
    const float* __restrict__ x3t, const float* __restrict__ p7,
    const float* __restrict__ W7vt, float* __restrict__ y7, float* __restrict__ partial) {
    __shared__ float vl[16][192];
    int item0 = blockIdx.x * 16;
    for (int i = threadIdx.x; i < 16 * 192; i += 256) {
        int it = i / 192, c = i % 192;
        const float* src = c < 64 ? x1t : (c < 128 ? x2t : x3t);
        vl[it][c] = src[((size_t)(item0 + it)) * 64 + (c & 63)];
    }
    __syncthreads();
    int o = threadIdx.x & 127, h = threadIdx.x >> 7;
    float acc[8] = {0};
    for (int c = 0; c < 192; c++) {
        float w = W7vt[c * 128 + o];
#pragma unroll
        for (int i = 0; i < 8; i++) acc[i] = fmaf(w, vl[h * 8 + i][c], acc[i]);
    }
    float s1 = 0, s2 = 0;
    for (int i = 0; i < 8; i++) {
        int item = item0 + h * 8 + i;
        int b = item / N_;
        float yv = p7[b * 128 + o] + acc[i];
        y7[(size_t)item * 128 + o] = yv;
        s1 += yv; s2 = fmaf(yv, yv, s2);
    }
    __shared__ float r1[256], r2[256];
    r1[threadIdx.x] = s1; r2[threadIdx.x] = s2;
    __syncthreads();
    if (threadIdx.x < 128) {
        float* sp = partial + (size_t)blockIdx.x * 256;
        sp[threadIdx.x] = r1[threadIdx.x] + r1[threadIdx.x + 128];
        sp[128 + threadIdx.x] = r2[threadIdx.x] + r2[threadIdx.x + 128];
    }
}

// ---------------------------------------------------------------- W8 conv (128->64), Wt-coalesced
__global__ __launch_bounds__(256) void k_conv_w8(
    const float* __restrict__ y7, const float* __restrict__ prm7,
    const float* __restrict__ W8t, float* __restrict__ y8, float* __restrict__ partial) {
    int lane = threadIdx.x & 63;
    int item = blockIdx.x * 4 + (threadIdx.x >> 6);
    float W0[64], W1r[64];
#pragma unroll
    for (int c = 0; c < 64; c++) {
        W0[c] = W8t[c * 64 + lane];
        W1r[c] = W8t[(64 + c) * 64 + lane];
    }
    float a0 = prm7[lane], sh0 = prm7[128 + lane];
    float a1 = prm7[64 + lane], sh1 = prm7[128 + 64 + lane];
    float z0 = lrelu(fmaf(a0, y7[(size_t)item * 128 + lane], sh0));
    float z1 = lrelu(fmaf(a1, y7[(size_t)item * 128 + 64 + lane], sh1));
    float acc = 0.f;
#pragma unroll
    for (int c = 0; c < 64; c++) {
        acc = fmaf(W0[c], __shfl(z0, c), acc);
        acc = fmaf(W1r[c], __shfl(z1, c), acc);
    }
    y8[(size_t)item * 64 + lane] = acc;
    STATS_STORE_64(acc, acc * acc, partial)
}

// ---------------------------------------------------------------- final: bn8+lrelu, W9t -> out
__global__ __launch_bounds__(256) void k_final(
    const float* __restrict__ y8, const float* __restrict__ prm8,
    const float* __restrict__ W9t, void* __restrict__ out, const int* __restrict__ flag) {
    __shared__ float zl[2][64];
    int item0 = blockIdx.x * 2;
    if (threadIdx.x < 128) {
        int it = threadIdx.x >> 6, c = threadIdx.x & 63;
        float z = fmaf(prm8[c], y8[(size_t)(item0 + it) * 64 + c], prm8[64 + c]);
        zl[it][c] = lrelu(z);
    }
    __syncthreads();
    int it = threadIdx.x >> 7, o = threadIdx.x & 127;
    float acc = 0.f;
#pragma unroll
    for (int c = 0; c < 64; c++) acc = fmaf(W9t[c * 128 + o], zl[it][c], acc);
    size_t oi = (size_t)(item0 + it) * 128 + o;
    if (*flag) ((bf16*)out)[oi] = __float2bfloat16(acc);
    else ((float*)out)[oi] = acc;
}

// ---------------------------------------------------------------- host
extern "C" void kernel_launch(void* const* d_in, const int* in_sizes, int n_in,
                              void* d_out, int out_size, void* d_ws, size_t ws_size,
                              hipStream_t stream) {
    (void)in_sizes; (void)n_in; (void)out_size; (void)ws_size;
    const void* x = d_in[0];
    const void* xgrid = d_in[1];
    const int* FPS = (const int*)d_in[2];

    char* ws = (char*)d_ws;
    size_t off = 0;
    auto alloc = [&](size_t bytes) -> char* {
        char* p = ws + off;
        off = (off + bytes + 255) & ~(size_t)255;
        return p;
    };
    int* flag       = (int*)alloc(256);
    int* counters   = (int*)alloc(256);
    float* partials = (float*)alloc(2048 * 128 * sizeof(float));   // 1 MB
    double* redbuf  = (double*)alloc(32 * 1024 * sizeof(double));  // 256 KB
    float* prm      = (float*)alloc(8 * 1024 * sizeof(float));
    static const int wsz[9] = {384, 4096, 8192, 4096, 8192, 98304, 90112, 8192, 8192};
    static const int dims[8] = {64, 64, 64, 64, 64, 512, 128, 64};
    float* cW[9];
    for (int i = 0; i < 9; i++) cW[i] = (float*)alloc((size_t)wsz[i] * 4);
    float* cG[8];
    float* cB[8];
    for (int j = 0; j < 8; j++) {
        cG[j] = (float*)alloc((size_t)dims[j] * 4);
        cB[j] = (float*)alloc((size_t)dims[j] * 4);
    }
    float* W6t  = (float*)alloc((size_t)512 * 192 * 4);
    float* W7vt = (float*)alloc((size_t)128 * 192 * 4);
    float* W8t  = (float*)alloc((size_t)64 * 128 * 4);
    float* W9t  = (float*)alloc((size_t)128 * 64 * 4);
    float* xt    = (float*)alloc((size_t)BN * 3 * 4);
    float* gt    = (float*)alloc((size_t)BM * 3 * 4);
    float* gT3   = (float*)alloc((size_t)B_ * 3 * M_ * 4);
    float* gn    = (float*)alloc((size_t)BM * 4);
    int* nearest = (int*)alloc((size_t)BN * 4);
    int* nbr     = (int*)alloc((size_t)BM * K_ * 4);
    float* Pg    = (float*)alloc((size_t)BM * 64 * 4);
    float* x1t   = (float*)alloc((size_t)BN * 64 * 4);
    float* x2t   = (float*)alloc((size_t)BN * 64 * 4);
    float* x3t   = (float*)alloc((size_t)BN * 64 * 4);
    float* x1gt  = (float*)alloc((size_t)BM * 64 * 4);
    float* x2gt  = (float*)alloc((size_t)BM * 64 * 4);
    float* gT64  = (float*)alloc((size_t)B_ * 64 * M_ * 4);
    float* y6    = (float*)alloc((size_t)BM * 512 * 4);
    float* xgmax = (float*)alloc((size_t)B_ * 512 * 4);
    float* p7    = (float*)alloc((size_t)B_ * 128 * 4);
    float* y7    = (float*)alloc((size_t)BN * 128 * 4);
    float* y8    = (float*)alloc((size_t)BN * 64 * 4);
    // Aliases (lifetimes verified; same layout as passing rounds):
    float* D0b = y7;
    float* S0b = y7 + (size_t)BN * 64;
    float* mnb = y8;
    float* mxb = y6;
    float* T1b = y6;
    float* T2b = y6 + (size_t)BM * 64;
    float* Mnb = y6 + (size_t)2 * BM * 64;
    float* Mxb = y6 + (size_t)3 * BM * 64;

    hipMemsetAsync(counters, 0, 8 * sizeof(int), stream);
    k_detect<<<1, 256, 0, stream>>>((const unsigned short*)x, flag);

    CvtArgs ca;
    for (int i = 0; i < 9; i++) ca.d[i] = {d_in[3 + i], cW[i], wsz[i]};
    for (int j = 0; j < 8; j++) {
        ca.d[9 + 2 * j]     = {d_in[12 + 2 * j], cG[j], dims[j]};
        ca.d[9 + 2 * j + 1] = {d_in[13 + 2 * j], cB[j], dims[j]};
    }
    k_convert<<<dim3(384, 25), 256, 0, stream>>>(ca, flag);
    CvtTArgs ct;
    ct.d[0] = {d_in[8],  W6t,  512, 192, 192, 0};    // W6
    ct.d[1] = {d_in[9],  W7vt, 128, 192, 704, 512};  // W7 variable cols
    ct.d[2] = {d_in[10], W8t,  64, 128, 128, 0};     // W8
    ct.d[3] = {d_in[11], W9t,  128, 64, 64, 0};      // W9
    k_convT<<<dim3(384, 4), 256, 0, stream>>>(ct, flag);
    k_transpose<<<(BN * 3 + BM + 255) / 256, 256, 0, stream>>>(x, xgrid, flag, xt, gt, gT3, gn);

    const int PG = BN / 4;         // wave-per-point grids (2048)
    const int EW = BN * 64 / 256;  // elementwise grids
    const int CK = BN * K_;

    // ---- stage A (D=3, W1,W2) ----
    k_pgrid3<<<BM / 4, 256, 0, stream>>>(gt, cW[0], Pg);
    k_knn3<<<BN / 16 + BM / 4, 256, 0, stream>>>(xt, gt, gT3, gn, Pg, nearest, nbr, T1b, T2b, Mnb, Mxb);
    k_prep_stats<3><<<PG, 256, 0, stream>>>(xt, cW[0], nearest, T1b, T2b, D0b, S0b, partials);
    k_redfin<2048, 64><<<32, 256, 0, stream>>>(partials, redbuf, counters + 0, CK, cG[0], cB[0], prm + 0 * 1024);
    k_pass1<<<PG, 256, 0, stream>>>(Pg, D0b, S0b, nearest, nbr, prm + 0 * 1024, cW[1], partials, mnb, mxb);
    k_redfin<2048, 64><<<32, 256, 0, stream>>>(partials, redbuf, counters + 1, CK, cG[1], cB[1], prm + 1 * 1024);
    k_apply<<<EW, 256, 0, stream>>>(mnb, mxb, prm + 1 * 1024, x1t);

    // ---- stage B (D=64, W3,W4) ----
    k_gridprep<<<BM / 4, 256, 0, stream>>>(x1t, FPS, cW[2], x1gt, gT64, gn, Pg);
    k_knn64<<<PG + BM / 4, 256, 0, stream>>>(x1t, x1gt, gT64, gn, Pg, nearest, nbr, T1b, T2b, Mnb, Mxb);
    k_prep_stats<64><<<PG, 256, 0, stream>>>(x1t, cW[2], nearest, T1b, T2b, D0b, S0b, partials);
    k_redfin<2048, 64><<<32, 256, 0, stream>>>(partials, redbuf, counters + 2, CK, cG[2], cB[2], prm + 2 * 1024);
    k_pass1<<<PG, 256, 0, stream>>>(Pg, D0b, S0b, nearest, nbr, prm + 2 * 1024, cW[3], partials, mnb, mxb);
    k_redfin<2048, 64><<<32, 256, 0, stream>>>(partials, redbuf, counters + 3, CK, cG[3], cB[3], prm + 3 * 1024);
    k_apply<<<EW, 256, 0, stream>>>(mnb, mxb, prm + 3 * 1024, x2t);

    // ---- stage C (D=64, W5 single conv) ----
    k_gridprep<<<BM / 4, 256, 0, stream>>>(x2t, FPS, cW[4], x2gt, gT64, gn, Pg);
    k_knn64<<<PG + BM / 4, 256, 0, stream>>>(x2t, x2gt, gT64, gn, Pg, nearest, nbr, T1b, T2b, Mnb, Mxb);
    k_prep_stats<64><<<PG, 256, 0, stream>>>(x2t, cW[4], nearest, T1b, T2b, D0b, S0b, partials);
    k_redfin<2048, 64><<<32, 256, 0, stream>>>(partials, redbuf, counters + 4, CK, cG[4], cB[4], prm + 4 * 1024);
    k_apply0<<<EW, 256, 0, stream>>>(D0b, S0b, nearest, Mnb, Mxb, prm + 4 * 1024, x3t);

    // ---- global MLP tail ----
    k_conv_w6<<<BM / 4, 256, 0, stream>>>(x1gt, x2gt, x3t, FPS, W6t, y6, partials);
    k_redfin<256, 512><<<32, 256, 0, stream>>>(partials, redbuf, counters + 5, BM, cG[5], cB[5], prm + 5 * 1024);
    k_maxM<<<B_ * 64, 256, 0, stream>>>(y6, prm + 5 * 1024, xgmax);
    k_p7<<<64, 256, 0, stream>>>(xgmax, cW[6], p7);
    k_conv_w7<<<BN / 16, 256, 0, stream>>>(x1t, x2t, x3t, p7, W7vt, y7, partials);
    k_redfin<512, 128><<<32, 256, 0, stream>>>(partials, redbuf, counters + 6, BN, cG[6], cB[6], prm + 6 * 1024);
    k_conv_w8<<<BN / 4, 256, 0, stream>>>(y7, prm + 6 * 1024, W8t, y8, partials);
    k_redfin<2048, 64><<<32, 256, 0, stream>>>(partials, redbuf, counters + 7, BN, cG[7], cB[7], prm + 7 * 1024);
    k_final<<<BN / 2, 256, 0, stream>>>(y8, prm + 7 * 1024, W9t, d_out, flag);
}

// Round 13
// 750.672 us; speedup vs baseline: 2.4518x; 1.0499x over previous
//
#include <hip/hip_runtime.h>
#include <hip/hip_bf16.h>

#define DEV __device__ __forceinline__
using bf16 = __hip_bfloat16;

static constexpr int B_ = 2, N_ = 4096, M_ = 512, K_ = 50;
static constexpr int BN = B_ * N_;   // 8192 points
static constexpr int BM = B_ * M_;   // 1024 grid points
static constexpr float EPS_ = 1e-5f;

DEV float lrelu(float z) { return z < 0.f ? 0.2f * z : z; }
DEV int clampi(int v, int hi) { return ((unsigned)v < (unsigned)hi) ? v : 0; }

// ---------------------------------------------------------------- dtype detect
__global__ void k_detect(const unsigned short* __restrict__ xw, int* __restrict__ flag) {
    int t = threadIdx.x;
    int cnt = 0;
    for (int i = t; i < 4096; i += 256) {
        int e = (xw[i] >> 7) & 0xFF;
        if (e >= 100 && e <= 140) cnt++;
    }
    __shared__ int sh[256];
    sh[t] = cnt;
    __syncthreads();
    for (int s = 128; s; s >>= 1) { if (t < s) sh[t] += sh[t + s]; __syncthreads(); }
    if (t == 0) *flag = (sh[0] >= 3300) ? 1 : 0;
}

// ---------------------------------------------------------------- convert params to f32
struct CvtDesc { const void* src; float* dst; int n; };
struct CvtArgs { CvtDesc d[25]; };
__global__ void k_convert(CvtArgs a, const int* __restrict__ flag) {
    CvtDesc dd = a.d[blockIdx.y];
    int i = blockIdx.x * 256 + threadIdx.x;
    if (i >= dd.n) return;
    float v = (*flag) ? __bfloat162float(((const bf16*)dd.src)[i])
                      : ((const float*)dd.src)[i];
    dd.dst[i] = v;
}

// ---------------------------------------------------------------- transposed weight copies
struct CvtT { const void* src; float* dst; int O; int C; int stride; int off; };
struct CvtTArgs { CvtT d[4]; };
__global__ void k_convT(CvtTArgs a, const int* __restrict__ flag) {
    CvtT dd = a.d[blockIdx.y];
    int idx = blockIdx.x * 256 + threadIdx.x;
    if (idx >= dd.O * dd.C) return;
    int c = idx / dd.O, o = idx % dd.O;
    int si = o * dd.stride + dd.off + c;
    float v = (*flag) ? __bfloat162float(((const bf16*)dd.src)[si])
                      : ((const float*)dd.src)[si];
    dd.dst[idx] = v;   // dst[c*O + o]
}

// ---------------------------------------------------------------- transpose (flat regrid; + gn for grid)
DEV float rdval(const void* p, int i, int isbf) {
    return isbf ? __bfloat162float(((const bf16*)p)[i]) : ((const float*)p)[i];
}
__global__ void k_transpose(const void* __restrict__ x, const void* __restrict__ xg,
                            const int* __restrict__ flag,
                            float* __restrict__ xt, float* __restrict__ gt,
                            float* __restrict__ gT3, float* __restrict__ gn) {
    int isbf = *flag;
    int idx = blockIdx.x * 256 + threadIdx.x;
    if (idx < BN * 3) {
        int c = idx / BN, i = idx % BN;
        int b = i / N_, n = i % N_;
        xt[i * 3 + c] = rdval(x, (b * 3 + c) * N_ + n, isbf);
    } else {
        int r = idx - BN * 3;
        if (r < BM) {
            int b = r / M_, m = r % M_;
            float s = 0.f;
            for (int c = 0; c < 3; c++) {
                float v = rdval(xg, (b * 3 + c) * M_ + m, isbf);
                gt[r * 3 + c] = v;
                gT3[(b * 3 + c) * M_ + m] = v;
                s = fmaf(v, v, s);
            }
            gn[r] = s;
        }
    }
}

// ---------------------------------------------------------------- nearest D=3 body
DEV void nearest3_body(int blk, const float* __restrict__ q, const float* __restrict__ gt,
                       const float* __restrict__ gn, int* __restrict__ nearest) {
    int sub = threadIdx.x & 15;
    int pt = blk * 16 + (threadIdx.x >> 4);
    int b = pt >> 12;
    float q0 = q[pt * 3], q1 = q[pt * 3 + 1], q2 = q[pt * 3 + 2];
    float qn = q0 * q0 + q1 * q1 + q2 * q2;
    const float* gb = gt + (size_t)b * M_ * 3;
    const float* gnb = gn + b * M_;
    float best = 1e30f; int bi = 0x7fffffff;
    for (int j = 0; j < 32; j++) {
        int m = sub + 16 * j;
        float dot = q0 * gb[m * 3] + q1 * gb[m * 3 + 1] + q2 * gb[m * 3 + 2];
        float dv = qn + gnb[m] - 2.f * dot;
        if (dv < best || (dv == best && m < bi)) { best = dv; bi = m; }
    }
    for (int off = 8; off; off >>= 1) {
        float ov = __shfl_xor(best, off);
        int oi = __shfl_xor(bi, off);
        if (ov < best || (ov == best && oi < bi)) { best = ov; bi = oi; }
    }
    if (sub == 0) nearest[pt] = clampi(bi, M_);
}

// ---------------------------------------------------------------- nearest D=64 body
// Two-phase qs[32] (register diet). Accumulation order of qn and d[] is the
// identical serial c=0..63 order as the full-array version -> bit-exact.
DEV void nearest64_body(int blk, const float* __restrict__ q, const float* __restrict__ gT,
                        const float* __restrict__ gn, int* __restrict__ nearest) {
    int lane = threadIdx.x & 63;
    int pt = blk * 4 + __builtin_amdgcn_readfirstlane(threadIdx.x >> 6);
    int b = pt >> 12;
    const float* qrow = q + (size_t)pt * 64;
    const float* gTb = gT + (size_t)b * 64 * M_;
    float qn = 0.f;
    float d[8] = {0.f, 0.f, 0.f, 0.f, 0.f, 0.f, 0.f, 0.f};
#pragma clang loop unroll(disable)
    for (int h = 0; h < 2; h++) {
        float qs[32];
#pragma unroll
        for (int j = 0; j < 32; j++) qs[j] = qrow[h * 32 + j];
#pragma unroll
        for (int j = 0; j < 32; j++) qn = fmaf(qs[j], qs[j], qn);
#pragma unroll
        for (int j = 0; j < 32; j++) {
            int c = h * 32 + j;
            float qc = qs[j];
            float4 g0 = *(const float4*)(gTb + c * M_ + 4 * lane);
            float4 g1 = *(const float4*)(gTb + c * M_ + 256 + 4 * lane);
            d[0] = fmaf(qc, g0.x, d[0]); d[1] = fmaf(qc, g0.y, d[1]);
            d[2] = fmaf(qc, g0.z, d[2]); d[3] = fmaf(qc, g0.w, d[3]);
            d[4] = fmaf(qc, g1.x, d[4]); d[5] = fmaf(qc, g1.y, d[5]);
            d[6] = fmaf(qc, g1.z, d[6]); d[7] = fmaf(qc, g1.w, d[7]);
        }
    }
    const float* gnb = gn + b * M_;
    float4 n0 = *(const float4*)(gnb + 4 * lane);
    float4 n1 = *(const float4*)(gnb + 256 + 4 * lane);
    float nn[8] = {n0.x, n0.y, n0.z, n0.w, n1.x, n1.y, n1.z, n1.w};
    float best = 1e30f; int bi = 0;
#pragma unroll
    for (int i = 0; i < 8; i++) {
        int m = (i < 4) ? (4 * lane + i) : (256 + 4 * lane + i - 4);
        float dv = qn + nn[i] - 2.f * d[i];
        if (dv < best || (dv == best && m < bi)) { best = dv; bi = m; }
    }
    for (int off = 32; off; off >>= 1) {
        float ov = __shfl_xor(best, off);
        int oi = __shfl_xor(bi, off);
        if (ov < best || (ov == best && oi < bi)) { best = ov; bi = oi; }
    }
    if (lane == 0) nearest[pt] = clampi(bi, M_);
}

// ---------------------------------------------------------------- grid KNN body + fused neighborhood stats
// D=64 path uses the same two-phase qs[32] diet (bit-exact order).
template <int D>
DEV void nbr2_body(int blk, const float* __restrict__ g, const float* __restrict__ gT,
                   const float* __restrict__ gn, const float* __restrict__ Pg,
                   int* __restrict__ nbr, float* __restrict__ T1, float* __restrict__ T2,
                   float* __restrict__ Mn, float* __restrict__ Mx) {
    int lane = threadIdx.x & 63, w = threadIdx.x >> 6;
    int row = blk * 4 + w;
    int b = row >> 9;
    const float* grow = g + (size_t)row * D;
    float qn = gn[row];
    const float* gTb = gT + (size_t)b * D * M_;
    const float* gnb = gn + b * M_;
    float d[8] = {0.f, 0.f, 0.f, 0.f, 0.f, 0.f, 0.f, 0.f};
    if constexpr (D == 3) {
        float qs[3];
#pragma unroll
        for (int c = 0; c < 3; c++) qs[c] = grow[c];
#pragma unroll
        for (int c = 0; c < 3; c++) {
            float qc = qs[c];
            float4 g0 = *(const float4*)(gTb + c * M_ + 4 * lane);
            float4 g1 = *(const float4*)(gTb + c * M_ + 256 + 4 * lane);
            d[0] = fmaf(qc, g0.x, d[0]); d[1] = fmaf(qc, g0.y, d[1]);
            d[2] = fmaf(qc, g0.z, d[2]); d[3] = fmaf(qc, g0.w, d[3]);
            d[4] = fmaf(qc, g1.x, d[4]); d[5] = fmaf(qc, g1.y, d[5]);
            d[6] = fmaf(qc, g1.z, d[6]); d[7] = fmaf(qc, g1.w, d[7]);
        }
    } else {
#pragma clang loop unroll(disable)
        for (int h = 0; h < 2; h++) {
            float qs[32];
#pragma unroll
            for (int j = 0; j < 32; j++) qs[j] = grow[h * 32 + j];
#pragma unroll
            for (int j = 0; j < 32; j++) {
                int c = h * 32 + j;
                float qc = qs[j];
                float4 g0 = *(const float4*)(gTb + c * M_ + 4 * lane);
                float4 g1 = *(const float4*)(gTb + c * M_ + 256 + 4 * lane);
                d[0] = fmaf(qc, g0.x, d[0]); d[1] = fmaf(qc, g0.y, d[1]);
                d[2] = fmaf(qc, g0.z, d[2]); d[3] = fmaf(qc, g0.w, d[3]);
                d[4] = fmaf(qc, g1.x, d[4]); d[5] = fmaf(qc, g1.y, d[5]);
                d[6] = fmaf(qc, g1.z, d[6]); d[7] = fmaf(qc, g1.w, d[7]);
            }
        }
    }
    float4 n0 = *(const float4*)(gnb + 4 * lane);
    float4 n1 = *(const float4*)(gnb + 256 + 4 * lane);
    float dd[8];
    dd[0] = qn + n0.x - 2.f * d[0]; dd[1] = qn + n0.y - 2.f * d[1];
    dd[2] = qn + n0.z - 2.f * d[2]; dd[3] = qn + n0.w - 2.f * d[3];
    dd[4] = qn + n1.x - 2.f * d[4]; dd[5] = qn + n1.y - 2.f * d[5];
    dd[6] = qn + n1.z - 2.f * d[6]; dd[7] = qn + n1.w - 2.f * d[7];
    int mreg[8];
#pragma unroll
    for (int i = 0; i < 8; i++) mreg[i] = (i < 4) ? (4 * lane + i) : (256 + 4 * lane + i - 4);
    int myIdx = 0;
    for (int it = 0; it < K_; it++) {
        float bv = 1e30f; int bi = 0x7fffffff;
#pragma unroll
        for (int i = 0; i < 8; i++) {
            if (dd[i] < bv || (dd[i] == bv && mreg[i] < bi)) { bv = dd[i]; bi = mreg[i]; }
        }
        for (int off = 32; off; off >>= 1) {
            float ov = __shfl_xor(bv, off);
            int oi = __shfl_xor(bi, off);
            if (ov < bv || (ov == bv && oi < bi)) { bv = ov; bi = oi; }
        }
        bi = clampi(bi, M_);
        if (lane == it) { myIdx = bi; nbr[(size_t)row * K_ + it] = bi; }
#pragma unroll
        for (int i = 0; i < 8; i++) if (mreg[i] == bi) dd[i] = 1e30f;
    }
    const float* Pgb = Pg + (size_t)b * M_ * 64;
    float t1 = 0.f, t2 = 0.f, mn = 1e30f, mx = -1e30f;
#pragma unroll 7
    for (int k = 1; k < K_; k++) {
        int idx = __shfl(myIdx, k);
        float v = Pgb[(size_t)idx * 64 + lane];
        t1 += v; t2 = fmaf(v, v, t2);
        mn = fminf(mn, v); mx = fmaxf(mx, v);
    }
    size_t o = (size_t)row * 64 + lane;
    T1[o] = t1; T2[o] = t2; Mn[o] = mn; Mx[o] = mx;
}

// ---------------------------------------------------------------- fused KNN launches
__global__ __launch_bounds__(256) void k_knn3(
    const float* __restrict__ q, const float* __restrict__ gt, const float* __restrict__ gT3,
    const float* __restrict__ gn, const float* __restrict__ Pg,
    int* __restrict__ nearest, int* __restrict__ nbr, float* __restrict__ T1,
    float* __restrict__ T2, float* __restrict__ Mn, float* __restrict__ Mx) {
    if (blockIdx.x < BN / 16) nearest3_body(blockIdx.x, q, gt, gn, nearest);
    else nbr2_body<3>(blockIdx.x - BN / 16, gt, gT3, gn, Pg, nbr, T1, T2, Mn, Mx);
}
__global__ __launch_bounds__(256) void k_knn64(
    const float* __restrict__ q, const float* __restrict__ xgt, const float* __restrict__ gT,
    const float* __restrict__ gn, const float* __restrict__ Pg,
    int* __restrict__ nearest, int* __restrict__ nbr, float* __restrict__ T1,
    float* __restrict__ T2, float* __restrict__ Mn, float* __restrict__ Mx) {
    if (blockIdx.x < BN / 4) nearest64_body(blockIdx.x, q, gT, gn, nearest);
    else nbr2_body<64>(blockIdx.x - BN / 4, xgt, gT, gn, Pg, nbr, T1, T2, Mn, Mx);
}

// ---------------------------------------------------------------- deterministic block stats store
#define STATS_STORE_64(s1v, s2v, partial)                                         \
    {                                                                             \
        __shared__ float r1_[256], r2_[256];                                      \
        r1_[threadIdx.x] = (s1v); r2_[threadIdx.x] = (s2v);                       \
        __syncthreads();                                                          \
        if (threadIdx.x < 64) {                                                   \
            int t_ = threadIdx.x;                                                 \
            float a1_ = r1_[t_] + r1_[t_ + 64] + r1_[t_ + 128] + r1_[t_ + 192];   \
            float a2_ = r2_[t_] + r2_[t_ + 64] + r2_[t_ + 128] + r2_[t_ + 192];   \
            float* sp_ = (partial) + (size_t)blockIdx.x * 128;                    \
            sp_[t_] = a1_; sp_[64 + t_] = a2_;                                    \
        }                                                                         \
    }

// ---------------------------------------------------------------- Pg for stage A (D=3)
__global__ __launch_bounds__(256) void k_pgrid3(const float* __restrict__ g,
                                                const float* __restrict__ W1,
                                                float* __restrict__ Pg) {
    int lane = threadIdx.x & 63;
    int row = blockIdx.x * 4 + __builtin_amdgcn_readfirstlane(threadIdx.x >> 6);
    float c0 = g[row * 3], c1 = g[row * 3 + 1], c2 = g[row * 3 + 2];
    const float* wr = W1 + lane * 6;
    Pg[(size_t)row * 64 + lane] = fmaf(wr[0], c0, fmaf(wr[1], c1, wr[2] * c2));
}

// ---------------------------------------------------------------- fused grid prep (stages B/C)
__global__ __launch_bounds__(256) void k_gridprep(
    const float* __restrict__ xsrc, const int* __restrict__ FPS,
    const float* __restrict__ W1, float* __restrict__ xgt, float* __restrict__ gT,
    float* __restrict__ gn, float* __restrict__ Pg) {
    int lane = threadIdx.x & 63, w = threadIdx.x >> 6;
    int row = blockIdx.x * 4 + w;
    int b = row >> 9, m = row & 511;
    int src = b * N_ + clampi(FPS[row], N_);
    float ge = xsrc[(size_t)src * 64 + lane];
    xgt[(size_t)row * 64 + lane] = ge;
    gT[((size_t)b * 64 + lane) * M_ + m] = ge;
    const float* wr = W1 + lane * 128;
    float s = 0.f, acc = 0.f;
#pragma unroll
    for (int c = 0; c < 64; c++) {
        float vc = __shfl(ge, c);
        s = fmaf(vc, vc, s);
        acc = fmaf(wr[c], vc, acc);
    }
    Pg[(size_t)row * 64 + lane] = acc;
    if (lane == 0) gn[row] = s;
}

// ---------------------------------------------------------------- fused prep + BN stats of y1
template <int D>
__global__ __launch_bounds__(256) void k_prep_stats(
    const float* __restrict__ q, const float* __restrict__ W1,
    const int* __restrict__ nearest, const float* __restrict__ T1,
    const float* __restrict__ T2, float* __restrict__ D0, float* __restrict__ S0,
    float* __restrict__ partial) {
    int lane = threadIdx.x & 63;
    int pt = blockIdx.x * 4 + __builtin_amdgcn_readfirstlane(threadIdx.x >> 6);
    int b = pt >> 12;
    float pa, pb;
    if constexpr (D == 3) {
        float c0 = q[pt * 3], c1 = q[pt * 3 + 1], c2 = q[pt * 3 + 2];
        const float* wr = W1 + lane * 6;
        pa = fmaf(wr[0], c0, fmaf(wr[1], c1, wr[2] * c2));
        pb = fmaf(wr[3], c0, fmaf(wr[4], c1, wr[5] * c2));
    } else {
        float ge = q[(size_t)pt * 64 + lane];
        const float* wr = W1 + lane * 128;
        pa = 0.f; pb = 0.f;
#pragma unroll
        for (int c = 0; c < 64; c++) {
            float sh = __shfl(ge, c);
            pa = fmaf(wr[c], sh, pa);
            pb = fmaf(wr[64 + c], sh, pb);
        }
    }
    float d0 = pb - pa, s0 = pb;
    size_t t = (size_t)pt * 64 + lane;
    D0[t] = d0;
    S0[t] = s0;
    size_t nr = ((size_t)b * M_ + clampi(nearest[pt], M_)) * 64 + lane;
    float t1 = T1[nr], t2 = T2[nr];
    float s1 = s0 + fmaf(49.f, d0, t1);
    float s2 = fmaf(s0, s0, fmaf(49.f * d0, d0, fmaf(2.f * d0, t1, t2)));
    STATS_STORE_64(s1, s2, partial)
}

// ---------------------------------------------------------------- stage-C output: bn+lrelu(max) exact
__global__ void k_apply0(const float* __restrict__ D0, const float* __restrict__ S0,
                         const int* __restrict__ nearest, const float* __restrict__ Mn,
                         const float* __restrict__ Mx, const float* __restrict__ prm,
                         float* __restrict__ xout) {
    int t = blockIdx.x * 256 + threadIdx.x;
    int pt = t >> 6, o = t & 63;
    int b = pt >> 12;
    size_t nr = ((size_t)b * M_ + clampi(nearest[pt], M_)) * 64 + o;
    float d0 = D0[t], s0 = S0[t];
    float a = prm[o], sh = prm[64 + o];
    float v = a > 0.f ? fmaxf(s0, d0 + Mx[nr]) : fminf(s0, d0 + Mn[nr]);
    xout[t] = lrelu(fmaf(a, v, sh));
}

// ---------------------------------------------------------------- pass1: bn1+lrelu -> conv2 -> stats+min/max
__global__ __launch_bounds__(256) void k_pass1(
    const float* __restrict__ Pg, const float* __restrict__ D0,
    const float* __restrict__ S0, const int* __restrict__ nearest,
    const int* __restrict__ nbr, const float* __restrict__ prm1,
    const float* __restrict__ W2, float* __restrict__ partial,
    float* __restrict__ mn_out, float* __restrict__ mx_out) {
    __shared__ float tile[4][64 * 17];
    __shared__ float ls1[256], ls2[256];
    int lane = threadIdx.x & 63;
    int wv = __builtin_amdgcn_readfirstlane(threadIdx.x >> 6);
    int pt = blockIdx.x * 4 + wv;
    int b = pt >> 12;
    int nr = clampi(nearest[pt], M_);
    const int* nrow = nbr + ((size_t)b * M_ + nr) * K_;
    int k = lane;
    int idx = (k >= 1 && k < K_) ? clampi(nrow[k], M_) : 0;
    const float4* src = (k == 0) ? (const float4*)(S0 + (size_t)pt * 64)
                                 : (const float4*)(Pg + ((size_t)b * M_ + idx) * 64);
    const float4* d0r = (const float4*)(D0 + (size_t)pt * 64);
    const float4* a4 = (const float4*)(prm1);
    const float4* s4 = (const float4*)(prm1 + 64);
    float dscale = (k == 0) ? 0.f : 1.f;
    float z[64];
#pragma unroll
    for (int c4 = 0; c4 < 16; c4++) {
        float4 v = src[c4]; float4 d = d0r[c4]; float4 a = a4[c4]; float4 s = s4[c4];
        z[4 * c4 + 0] = lrelu(fmaf(a.x, fmaf(dscale, d.x, v.x), s.x));
        z[4 * c4 + 1] = lrelu(fmaf(a.y, fmaf(dscale, d.y, v.y), s.y));
        z[4 * c4 + 2] = lrelu(fmaf(a.z, fmaf(dscale, d.z, v.z), s.z));
        z[4 * c4 + 3] = lrelu(fmaf(a.w, fmaf(dscale, d.w, v.w), s.w));
    }
    float* tl = tile[wv];
    int o_l = lane & 15, kg = lane >> 4;
#pragma clang loop unroll(disable)
    for (int ch = 0; ch < 4; ch++) {
#pragma clang loop unroll(disable)
        for (int og = 0; og < 4; og++) {
            int obase = ch * 16 + og * 4;
            const float4* wr0 = (const float4*)(W2 + (obase + 0) * 64);
            const float4* wr1 = (const float4*)(W2 + (obase + 1) * 64);
            const float4* wr2 = (const float4*)(W2 + (obase + 2) * 64);
            const float4* wr3 = (const float4*)(W2 + (obase + 3) * 64);
            float a0 = 0.f, a1 = 0.f, a2 = 0.f, a3 = 0.f;
#pragma unroll
            for (int c4 = 0; c4 < 16; c4++) {
                float z0 = z[4 * c4 + 0], z1 = z[4 * c4 + 1];
                float z2 = z[4 * c4 + 2], z3 = z[4 * c4 + 3];
                float4 w0 = wr0[c4], w1 = wr1[c4], w2 = wr2[c4], w3 = wr3[c4];
                a0 = fmaf(w0.x, z0, a0); a0 = fmaf(w0.y, z1, a0);
                a0 = fmaf(w0.z, z2, a0); a0 = fmaf(w0.w, z3, a0);
                a1 = fmaf(w1.x, z0, a1); a1 = fmaf(w1.y, z1, a1);
                a1 = fmaf(w1.z, z2, a1); a1 = fmaf(w1.w, z3, a1);
                a2 = fmaf(w2.x, z0, a2); a2 = fmaf(w2.y, z1, a2);
                a2 = fmaf(w2.z, z2, a2); a2 = fmaf(w2.w, z3, a2);
                a3 = fmaf(w3.x, z0, a3); a3 = fmaf(w3.y, z1, a3);
                a3 = fmaf(w3.z, z2, a3); a3 = fmaf(w3.w, z3, a3);
            }
            tl[lane * 17 + og * 4 + 0] = a0;
            tl[lane * 17 + og * 4 + 1] = a1;
            tl[lane * 17 + og * 4 + 2] = a2;
            tl[lane * 17 + og * 4 + 3] = a3;
        }
        float p1 = 0.f, p2 = 0.f, pm = -1e30f, pn = 1e30f;
#pragma unroll
        for (int i = 0; i < 16; i++) {
            int kk = kg * 16 + i;
            if (kk < K_) {
                float v = tl[kk * 17 + o_l];
                p1 += v; p2 = fmaf(v, v, p2);
                pm = fmaxf(pm, v); pn = fminf(pn, v);
            }
        }
        p1 += __shfl_xor(p1, 16); p1 += __shfl_xor(p1, 32);
        p2 += __shfl_xor(p2, 16); p2 += __shfl_xor(p2, 32);
        pm = fmaxf(pm, __shfl_xor(pm, 16)); pm = fmaxf(pm, __shfl_xor(pm, 32));
        pn = fminf(pn, __shfl_xor(pn, 16)); pn = fminf(pn, __shfl_xor(pn, 32));
        if (lane < 16) {
            int o = ch * 16 + lane;
            mn_out[(size_t)pt * 64 + o] = pn;
            mx_out[(size_t)pt * 64 + o] = pm;
            ls1[wv * 64 + o] = p1;
            ls2[wv * 64 + o] = p2;
        }
    }
    __syncthreads();
    if (threadIdx.x < 64) {
        int t = threadIdx.x;
        float a1 = ls1[t] + ls1[64 + t] + ls1[128 + t] + ls1[192 + t];
        float a2 = ls2[t] + ls2[64 + t] + ls2[128 + t] + ls2[192 + t];
        float* sp = partial + (size_t)blockIdx.x * 128;
        sp[t] = a1; sp[64 + t] = a2;
    }
}

// ---------------------------------------------------------------- apply bn+lrelu to min/max (exact)
__global__ void k_apply(const float* __restrict__ mn, const float* __restrict__ mx,
                        const float* __restrict__ prm, float* __restrict__ xout) {
    int t = blockIdx.x * 256 + threadIdx.x;
    int o = t & 63;
    float a = prm[o], sh = prm[64 + o];
    float v = a > 0.f ? mx[t] : mn[t];
    xout[t] = lrelu(fmaf(a, v, sh));
}

// ---------------------------------------------------------------- fused reduce+finalize (32 blocks)
template <int NP, int O>
__global__ __launch_bounds__(256) void k_redfin(
    const float* __restrict__ partial, double* __restrict__ red,
    int* __restrict__ counter, int C,
    const float* __restrict__ g, const float* __restrict__ bt,
    float* __restrict__ prm) {
    constexpr int VALS = 2 * O;
    constexpr int G = NP / 32;
    int b = blockIdx.x;   // 32 blocks
    for (int v = threadIdx.x; v < VALS; v += 256) {
        const float* p = partial + (size_t)b * G * VALS + v;
        double s = 0.0;
#pragma unroll
        for (int k = 0; k < G; k++) s += p[(size_t)k * VALS];
        red[(size_t)b * VALS + v] = s;
    }
    __threadfence();
    __syncthreads();
    __shared__ bool isLast;
    if (threadIdx.x == 0) isLast = (atomicAdd(counter, 1) == 31);
    __syncthreads();
    if (!isLast) return;
    __threadfence();
    for (int o = threadIdx.x; o < O; o += 256) {
        double s1 = 0.0, s2 = 0.0;
#pragma unroll
        for (int k = 0; k < 32; k++) {
            s1 += red[(size_t)k * VALS + o];
            s2 += red[(size_t)k * VALS + O + o];
        }
        double m = s1 / C, var = s2 / C - m * m;
        if (var < 0) var = 0;
        float sc = g[o] / sqrtf((float)var + EPS_);
        prm[o] = sc;
        prm[O + o] = bt[o] - (float)m * sc;
    }
}

// ---------------------------------------------------------------- W6 conv (192->512), Wt-coalesced, 4-row tiles
__global__ __launch_bounds__(256) void k_conv_w6(
    const float* __restrict__ x1gt, const float* __restrict__ x2gt,
    const float* __restrict__ x3t, const int* __restrict__ FPS,
    const float* __restrict__ W6t, float* __restrict__ y6, float* __restrict__ partial) {
    __shared__ float vl[4][192];
    int b = blockIdx.x / 128;
    int m0 = (blockIdx.x % 128) * 4;
    for (int i = threadIdx.x; i < 4 * 192; i += 256) {
        int mi = i / 192, c = i % 192;
        float v;
        if (c < 128) {
            const float* src = c < 64 ? x1gt : x2gt;
            v = src[((size_t)b * M_ + m0 + mi) * 64 + (c & 63)];
        } else {
            int s = b * N_ + clampi(FPS[b * M_ + m0 + mi], N_);
            v = x3t[(size_t)s * 64 + (c - 128)];
        }
        vl[mi][c] = v;
    }
    __syncthreads();
    float acc0[4] = {0}, acc1[4] = {0};
    int o0 = threadIdx.x, o1 = threadIdx.x + 256;
    for (int c = 0; c < 192; c++) {
        float w0 = W6t[c * 512 + o0];
        float w1 = W6t[c * 512 + o1];
#pragma unroll
        for (int m = 0; m < 4; m++) { float v = vl[m][c]; acc0[m] = fmaf(w0, v, acc0[m]); acc1[m] = fmaf(w1, v, acc1[m]); }
    }
    float s1a = 0, s2a = 0, s1b = 0, s2b = 0;
    for (int m = 0; m < 4; m++) {
        float ya = acc0[m], yb = acc1[m];
        y6[((size_t)b * M_ + m0 + m) * 512 + o0] = ya;
        y6[((size_t)b * M_ + m0 + m) * 512 + o1] = yb;
        s1a += ya; s2a = fmaf(ya, ya, s2a); s1b += yb; s2b = fmaf(yb, yb, s2b);
    }
    float* sp = partial + (size_t)blockIdx.x * 1024;
    sp[o0] = s1a; sp[512 + o0] = s2a;
    sp[o1] = s1b; sp[512 + o1] = s2b;
}

// ---------------------------------------------------------------- bn6+lrelu+max over M (128 blocks)
__global__ void k_maxM(const float* __restrict__ y6, const float* __restrict__ prm,
                       float* __restrict__ xgmax) {
    int blk = blockIdx.x;            // B_*64
    int b = blk >> 6;
    int obase = (blk & 63) << 3;
    int o = obase + (threadIdx.x & 7);
    int mg = threadIdx.x >> 3;       // 32 m-groups
    float a = prm[o], sh = prm[512 + o];
    float mx = -1e30f;
    for (int m = mg; m < M_; m += 32)
        mx = fmaxf(mx, lrelu(fmaf(a, y6[((size_t)b * M_ + m) * 512 + o], sh)));
    __shared__ float red[256];
    red[threadIdx.x] = mx;
    __syncthreads();
    for (int s = 128; s >= 8; s >>= 1) {
        if (threadIdx.x < s) red[threadIdx.x] = fmaxf(red[threadIdx.x], red[threadIdx.x + s]);
        __syncthreads();
    }
    if (threadIdx.x < 8) xgmax[b * 512 + obase + threadIdx.x] = red[threadIdx.x];
}

// ---------------------------------------------------------------- P7: wave per output (fixed xor tree)
__global__ __launch_bounds__(256) void k_p7(const float* __restrict__ xgmax,
                                            const float* __restrict__ W7,
                                            float* __restrict__ p7) {
    int lane = threadIdx.x & 63, w = threadIdx.x >> 6;
    int t = blockIdx.x * 4 + w;     // 0..255
    int b = t >> 7, o = t & 127;
    float acc = 0.f;
#pragma unroll
    for (int j = 0; j < 8; j++) {
        int c = j * 64 + lane;
        acc = fmaf(W7[o * 704 + c], xgmax[b * 512 + c], acc);
    }
    for (int off = 32; off; off >>= 1) acc += __shfl_xor(acc, off);
    if (lane == 0) p7[t] = acc;
}

// ---------------------------------------------------------------- W7 conv (704->128), Wt-coalesced
__global__ __launch_bounds__(256) void k_conv_w7(
    const float* __restrict__ x1t, const float* __restrict__ x2t,
    const float* __restrict__ x3t, const float* __restrict__ p7,
    const float* __restrict__ W7vt, float* __restrict__ y7, float* __restrict__ partial) {
    __shared__ float vl[16][192];
    int item0 = blockIdx.x * 16;
    for (int i = threadIdx.x; i < 16 * 192; i += 256) {
        int it = i / 192, c = i % 192;
        const float* src = c < 64 ? x1t : (c < 128 ? x2t : x3t);
        vl[it][c] = src[((size_t)(item0 + it)) * 64 + (c & 63)];
    }
    __syncthreads();
    int o = threadIdx.x & 127, h = threadIdx.x >> 7;
    float acc[8] = {0};
    for (int c = 0; c < 192; c++) {
        float w = W7vt[c * 128 + o];
#pragma unroll
        for (int i = 0; i < 8; i++) acc[i] = fmaf(w, vl[h * 8 + i][c], acc[i]);
    }
    float s1 = 0, s2 = 0;
    for (int i = 0; i < 8; i++) {
        int item = item0 + h * 8 + i;
        int b = item / N_;
        float yv = p7[b * 128 + o] + acc[i];
        y7[(size_t)item * 128 + o] = yv;
        s1 += yv; s2 = fmaf(yv, yv, s2);
    }
    __shared__ float r1[256], r2[256];
    r1[threadIdx.x] = s1; r2[threadIdx.x] = s2;
    __syncthreads();
    if (threadIdx.x < 128) {
        float* sp = partial + (size_t)blockIdx.x * 256;
        sp[threadIdx.x] = r1[threadIdx.x] + r1[threadIdx.x + 128];
        sp[128 + threadIdx.x] = r2[threadIdx.x] + r2[threadIdx.x + 128];
    }
}

// ---------------------------------------------------------------- W8 conv (128->64), Wt-coalesced
__global__ __launch_bounds__(256) void k_conv_w8(
    const float* __restrict__ y7, const float* __restrict__ prm7,
    const float* __restrict__ W8t, float* __restrict__ y8, float* __restrict__ partial) {
    int lane = threadIdx.x & 63;
    int item = blockIdx.x * 4 + (threadIdx.x >> 6);
    float W0[64], W1r[64];
#pragma unroll
    for (int c = 0; c < 64; c++) {
        W0[c] = W8t[c * 64 + lane];
        W1r[c] = W8t[(64 + c) * 64 + lane];
    }
    float a0 = prm7[lane], sh0 = prm7[128 + lane];
    float a1 = prm7[64 + lane], sh1 = prm7[128 + 64 + lane];
    float z0 = lrelu(fmaf(a0, y7[(size_t)item * 128 + lane], sh0));
    float z1 = lrelu(fmaf(a1, y7[(size_t)item * 128 + 64 + lane], sh1));
    float acc = 0.f;
#pragma unroll
    for (int c = 0; c < 64; c++) {
        acc = fmaf(W0[c], __shfl(z0, c), acc);
        acc = fmaf(W1r[c], __shfl(z1, c), acc);
    }
    y8[(size_t)item * 64 + lane] = acc;
    STATS_STORE_64(acc, acc * acc, partial)
}

// ---------------------------------------------------------------- final: bn8+lrelu, W9t -> out
__global__ __launch_bounds__(256) void k_final(
    const float* __restrict__ y8, const float* __restrict__ prm8,
    const float* __restrict__ W9t, void* __restrict__ out, const int* __restrict__ flag) {
    __shared__ float zl[2][64];
    int item0 = blockIdx.x * 2;
    if (threadIdx.x < 128) {
        int it = threadIdx.x >> 6, c = threadIdx.x & 63;
        float z = fmaf(prm8[c], y8[(size_t)(item0 + it) * 64 + c], prm8[64 + c]);
        zl[it][c] = lrelu(z);
    }
    __syncthreads();
    int it = threadIdx.x >> 7, o = threadIdx.x & 127;
    float acc = 0.f;
#pragma unroll
    for (int c = 0; c < 64; c++) acc = fmaf(W9t[c * 128 + o], zl[it][c], acc);
    size_t oi = (size_t)(item0 + it) * 128 + o;
    if (*flag) ((bf16*)out)[oi] = __float2bfloat16(acc);
    else ((float*)out)[oi] = acc;
}

// ---------------------------------------------------------------- host
extern "C" void kernel_launch(void* const* d_in, const int* in_sizes, int n_in,
                              void* d_out, int out_size, void* d_ws, size_t ws_size,
                              hipStream_t stream) {
    (void)in_sizes; (void)n_in; (void)out_size; (void)ws_size;
    const void* x = d_in[0];
    const void* xgrid = d_in[1];
    const int* FPS = (const int*)d_in[2];

    char* ws = (char*)d_ws;
    size_t off = 0;
    auto alloc = [&](size_t bytes) -> char* {
        char* p = ws + off;
        off = (off + bytes + 255) & ~(size_t)255;
        return p;
    };
    int* flag       = (int*)alloc(256);
    int* counters   = (int*)alloc(256);
    float* partials = (float*)alloc(2048 * 128 * sizeof(float));   // 1 MB
    double* redbuf  = (double*)alloc(32 * 1024 * sizeof(double));  // 256 KB
    float* prm      = (float*)alloc(8 * 1024 * sizeof(float));
    static const int wsz[9] = {384, 4096, 8192, 4096, 8192, 98304, 90112, 8192, 8192};
    static const int dims[8] = {64, 64, 64, 64, 64, 512, 128, 64};
    float* cW[9];
    for (int i = 0; i < 9; i++) cW[i] = (float*)alloc((size_t)wsz[i] * 4);
    float* cG[8];
    float* cB[8];
    for (int j = 0; j < 8; j++) {
        cG[j] = (float*)alloc((size_t)dims[j] * 4);
        cB[j] = (float*)alloc((size_t)dims[j] * 4);
    }
    float* W6t  = (float*)alloc((size_t)512 * 192 * 4);
    float* W7vt = (float*)alloc((size_t)128 * 192 * 4);
    float* W8t  = (float*)alloc((size_t)64 * 128 * 4);
    float* W9t  = (float*)alloc((size_t)128 * 64 * 4);
    float* xt    = (float*)alloc((size_t)BN * 3 * 4);
    float* gt    = (float*)alloc((size_t)BM * 3 * 4);
    float* gT3   = (float*)alloc((size_t)B_ * 3 * M_ * 4);
    float* gn    = (float*)alloc((size_t)BM * 4);
    int* nearest = (int*)alloc((size_t)BN * 4);
    int* nbr     = (int*)alloc((size_t)BM * K_ * 4);
    float* Pg    = (float*)alloc((size_t)BM * 64 * 4);
    float* x1t   = (float*)alloc((size_t)BN * 64 * 4);
    float* x2t   = (float*)alloc((size_t)BN * 64 * 4);
    float* x3t   = (float*)alloc((size_t)BN * 64 * 4);
    float* x1gt  = (float*)alloc((size_t)BM * 64 * 4);
    float* x2gt  = (float*)alloc((size_t)BM * 64 * 4);
    float* gT64  = (float*)alloc((size_t)B_ * 64 * M_ * 4);
    float* y6    = (float*)alloc((size_t)BM * 512 * 4);
    float* xgmax = (float*)alloc((size_t)B_ * 512 * 4);
    float* p7    = (float*)alloc((size_t)B_ * 128 * 4);
    float* y7    = (float*)alloc((size_t)BN * 128 * 4);
    float* y8    = (float*)alloc((size_t)BN * 64 * 4);
    // Aliases (lifetimes verified; same layout as passing rounds):
    float* D0b = y7;
    float* S0b = y7 + (size_t)BN * 64;
    float* mnb = y8;
    float* mxb = y6;
    float* T1b = y6;
    float* T2b = y6 + (size_t)BM * 64;
    float* Mnb = y6 + (size_t)2 * BM * 64;
    float* Mxb = y6 + (size_t)3 * BM * 64;

    hipMemsetAsync(counters, 0, 8 * sizeof(int), stream);
    k_detect<<<1, 256, 0, stream>>>((const unsigned short*)x, flag);

    CvtArgs ca;
    for (int i = 0; i < 9; i++) ca.d[i] = {d_in[3 + i], cW[i], wsz[i]};
    for (int j = 0; j < 8; j++) {
        ca.d[9 + 2 * j]     = {d_in[12 + 2 * j], cG[j], dims[j]};
        ca.d[9 + 2 * j + 1] = {d_in[13 + 2 * j], cB[j], dims[j]};
    }
    k_convert<<<dim3(384, 25), 256, 0, stream>>>(ca, flag);
    CvtTArgs ct;
    ct.d[0] = {d_in[8],  W6t,  512, 192, 192, 0};    // W6
    ct.d[1] = {d_in[9],  W7vt, 128, 192, 704, 512};  // W7 variable cols
    ct.d[2] = {d_in[10], W8t,  64, 128, 128, 0};     // W8
    ct.d[3] = {d_in[11], W9t,  128, 64, 64, 0};      // W9
    k_convT<<<dim3(384, 4), 256, 0, stream>>>(ct, flag);
    k_transpose<<<(BN * 3 + BM + 255) / 256, 256, 0, stream>>>(x, xgrid, flag, xt, gt, gT3, gn);

    const int PG = BN / 4;         // wave-per-point grids (2048)
    const int EW = BN * 64 / 256;  // elementwise grids
    const int CK = BN * K_;

    // ---- stage A (D=3, W1,W2) ----
    k_pgrid3<<<BM / 4, 256, 0, stream>>>(gt, cW[0], Pg);
    k_knn3<<<BN / 16 + BM / 4, 256, 0, stream>>>(xt, gt, gT3, gn, Pg, nearest, nbr, T1b, T2b, Mnb, Mxb);
    k_prep_stats<3><<<PG, 256, 0, stream>>>(xt, cW[0], nearest, T1b, T2b, D0b, S0b, partials);
    k_redfin<2048, 64><<<32, 256, 0, stream>>>(partials, redbuf, counters + 0, CK, cG[0], cB[0], prm + 0 * 1024);
    k_pass1<<<PG, 256, 0, stream>>>(Pg, D0b, S0b, nearest, nbr, prm + 0 * 1024, cW[1], partials, mnb, mxb);
    k_redfin<2048, 64><<<32, 256, 0, stream>>>(partials, redbuf, counters + 1, CK, cG[1], cB[1], prm + 1 * 1024);
    k_apply<<<EW, 256, 0, stream>>>(mnb, mxb, prm + 1 * 1024, x1t);

    // ---- stage B (D=64, W3,W4) ----
    k_gridprep<<<BM / 4, 256, 0, stream>>>(x1t, FPS, cW[2], x1gt, gT64, gn, Pg);
    k_knn64<<<PG + BM / 4, 256, 0, stream>>>(x1t, x1gt, gT64, gn, Pg, nearest, nbr, T1b, T2b, Mnb, Mxb);
    k_prep_stats<64><<<PG, 256, 0, stream>>>(x1t, cW[2], nearest, T1b, T2b, D0b, S0b, partials);
    k_redfin<2048, 64><<<32, 256, 0, stream>>>(partials, redbuf, counters + 2, CK, cG[2], cB[2], prm + 2 * 1024);
    k_pass1<<<PG, 256, 0, stream>>>(Pg, D0b, S0b, nearest, nbr, prm + 2 * 1024, cW[3], partials, mnb, mxb);
    k_redfin<2048, 64><<<32, 256, 0, stream>>>(partials, redbuf, counters + 3, CK, cG[3], cB[3], prm + 3 * 1024);
    k_apply<<<EW, 256, 0, stream>>>(mnb, mxb, prm + 3 * 1024, x2t);

    // ---- stage C (D=64, W5 single conv) ----
    k_gridprep<<<BM / 4, 256, 0, stream>>>(x2t, FPS, cW[4], x2gt, gT64, gn, Pg);
    k_knn64<<<PG + BM / 4, 256, 0, stream>>>(x2t, x2gt, gT64, gn, Pg, nearest, nbr, T1b, T2b, Mnb, Mxb);
    k_prep_stats<64><<<PG, 256, 0, stream>>>(x2t, cW[4], nearest, T1b, T2b, D0b, S0b, partials);
    k_redfin<2048, 64><<<32, 256, 0, stream>>>(partials, redbuf, counters + 4, CK, cG[4], cB[4], prm + 4 * 1024);
    k_apply0<<<EW, 256, 0, stream>>>(D0b, S0b, nearest, Mnb, Mxb, prm + 4 * 1024, x3t);

    // ---- global MLP tail ----
    k_conv_w6<<<BM / 4, 256, 0, stream>>>(x1gt, x2gt, x3t, FPS, W6t, y6, partials);
    k_redfin<256, 512><<<32, 256, 0, stream>>>(partials, redbuf, counters + 5, BM, cG[5], cB[5], prm + 5 * 1024);
    k_maxM<<<B_ * 64, 256, 0, stream>>>(y6, prm + 5 * 1024, xgmax);
    k_p7<<<64, 256, 0, stream>>>(xgmax, cW[6], p7);
    k_conv_w7<<<BN / 16, 256, 0, stream>>>(x1t, x2t, x3t, p7, W7vt, y7, partials);
    k_redfin<512, 128><<<32, 256, 0, stream>>>(partials, redbuf, counters + 6, BN, cG[6], cB[6], prm + 6 * 1024);
    k_conv_w8<<<BN / 4, 256, 0, stream>>>(y7, prm + 6 * 1024, W8t, y8, partials);
    k_redfin<2048, 64><<<32, 256, 0, stream>>>(partials, redbuf, counters + 7, BN, cG[7], cB[7], prm + 7 * 1024);
    k_final<<<BN / 2, 256, 0, stream>>>(y8, prm + 7 * 1024, W9t, d_out, flag);
}